// Round 10
// baseline (616.436 us; speedup 1.0000x reference)
//
#include <hip/hip_runtime.h>

#define DEV __device__ __forceinline__

#define Dd   64
#define Bb   1024
#define Mm   32
#define Kk   16
#define Ll   8
#define NKGk 65536
#define NH   32768            // B*M
#define ROWS (NH + 2*Bb)      // 34816
#define NGRU (ROWS/64)        // 544 gru blocks
#define NAGG (ROWS/32)        // 1088 agg blocks
#define NKGB 256              // kg blocks (512 thr each -> 131072 items)

typedef float v2f __attribute__((ext_vector_type(2)));

// ---- workspace layout (float offsets) ----
#define OFF_WTATT   0          // 64x64  transposed W_tatt
#define OFF_WGS     4096       // 64x64  transposed W_gatt[:, :64]
#define OFF_WCOMB   8192       // 128x64 transposed (W_gatt[:,64:] @ W_re)
#define OFF_WRE     16384      // 128x64 transposed W_re
#define OFF_WAGG    24576      // 128x64 transposed W_agg
#define OFF_WU      32768      // 192x64 transposed W_u_mlp
#define OFF_GVEC    45056      // 64     sigmoid(gate)
#define OFF_USERG   45120      // 1024x64
#define OFF_UATT    110656     // 1024x64
#define OFF_SELFH   176192     // 32768x64
#define OFF_HISLC   2273344    // 32768x64
#define OFF_HISGB   4370496    // 32768x64
#define OFF_SELFPN  6467648    // 2x1024x64 (pos, then neg)
#define OFF_LCPN    6598720    // 2x1024x64
#define OFF_GBPN    6729792    // 2x1024x64
// Round-10: KGS relocated into the dead ULCPN region (unused since the round-8
// rsatt+umlp in-wave fusion). This removes the KGS/weight-pack overlay hazard and
// lets kg blocks run INSIDE fused_kernel concurrently with gru (which reads packs).
#define OFF_KGS     6860864    // 2x65536 kg squared distances (pos, neg) -> ends 6992000
#define OFF_KGSUM   7123008    // 1
#define OFF_WIHP    7123072    // 16x8x(4x3x8) = 12288  W_ih packed [jc][w][jj][gate][oi]
#define OFF_WHHP    7135360    // 12288                 W_hh packed
#define OFF_WAGP    7147648    // 32x8x(4x8)   = 8192   W_agg packed [jc][w][jj][oi]
#define OFF_RELC    7155840    // 65x64  (Wcomb_hi @ rel_emb[r])
#define OFF_RELR    7160000    // 65x64  (Wre_hi   @ rel_emb[r])

DEV float4 ld4(const float* p){ return *reinterpret_cast<const float4*>(p); }
DEV void st4(float* p, const float4 v){ *reinterpret_cast<float4*>(p) = v; }

DEV float tanh_fast(float x){
  float cx = fminf(15.f, fmaxf(-15.f, x));
  float e = __expf(2.f*cx);
  return __fdividef(e - 1.f, e + 1.f);
}
DEV float sigmoid_fast(float x){ return __fdividef(1.f, 1.f + __expf(-x)); }

// pk_fma matvec step: acc2[32] v2f pairs
#define MVJ2(ACC2_, WROW_, XX_) { \
  _Pragma("unroll") for (int d4_ = 0; d4_ < 16; ++d4_){ \
    float4 w_ = *(const float4*)((WROW_) + 4*d4_); \
    ACC2_[2*d4_]   += (v2f){w_.x, w_.y}*(XX_); \
    ACC2_[2*d4_+1] += (v2f){w_.z, w_.w}*(XX_); } }

// ---------------- prep1: transposes + packs + gate (32 blocks) ----------------
__global__ void prep1_kernel(const float* __restrict__ W_tatt, const float* __restrict__ W_gatt,
                             const float* __restrict__ W_re, const float* __restrict__ W_agg,
                             const float* __restrict__ W_u, const float* __restrict__ W_ih,
                             const float* __restrict__ W_hh, const float* __restrict__ gate,
                             float* __restrict__ ws)
{
  int g = blockIdx.x*256 + threadIdx.x;     // 0..8191
  for (int i = g; i < 4096; i += 8192){
    int d = i >> 6, j = i & 63;
    ws[OFF_WTATT + j*64 + d] = W_tatt[i];
    ws[OFF_WGS   + j*64 + d] = W_gatt[d*128 + j];
  }
  for (int i = g; i < 8192; i += 8192){
    int j = i >> 6, d = i & 63;
    ws[OFF_WRE  + i] = W_re[d*128 + j];
    ws[OFF_WAGG + i] = W_agg[d*128 + j];
    float s = 0.f;
    for (int dp = 0; dp < 64; ++dp) s += W_gatt[d*128 + 64 + dp] * W_re[dp*128 + j];
    ws[OFF_WCOMB + i] = s;
  }
  for (int i = g; i < 12288; i += 8192){
    int j = i >> 6, d = i & 63;
    ws[OFF_WU + i] = W_u[d*192 + j];
  }
  for (int i = g; i < 12288; i += 8192){
    int jc = i / 768, r1 = i - jc*768;
    int ww = r1 / 96,  r2 = r1 - ww*96;
    int jj = r2 / 24,  r3 = r2 - jj*24;
    int gg = r3 >> 3,  oi = r3 & 7;
    int j = jc*4 + jj, o = gg*64 + ww*8 + oi;
    ws[OFF_WIHP + i] = W_ih[o*64 + j];
    ws[OFF_WHHP + i] = W_hh[o*64 + j];
  }
  for (int i = g; i < 8192; i += 8192){
    int jc = i >> 8, r1 = i & 255;
    int ww = r1 >> 5, r2 = r1 & 31;
    int jj = r2 >> 3, oi = r2 & 7;
    ws[OFF_WAGP + i] = W_agg[(ww*8 + oi)*128 + jc*4 + jj];
  }
  if (g < 64) ws[OFF_GVEC + g] = sigmoid_fast(gate[g]);
}

// ---------------- prep2: rel tables (bid<17) + user gather/u_att (bid>=17) ----------------
// Round-10: user_prep merged in (both depend only on prep1) -> one fewer launch.
__global__ void prep2_kernel(const float* __restrict__ relation,
                             const int* __restrict__ uidx, const float* __restrict__ user_emb,
                             const float* __restrict__ b_tatt, float* __restrict__ ws)
{
  int bid = blockIdx.x;
  if (bid < 17){
    int i = bid*256 + threadIdx.x;          // 4352 >= 4160
    if (i >= 4160) return;
    int r = i >> 6, d = i & 63;
    const float* re = relation + r*64;
    float s1 = 0.f, s2 = 0.f;
    for (int j = 0; j < 64; ++j){
      s1 += ws[OFF_WCOMB + (64+j)*64 + d] * re[j];
      s2 += ws[OFF_WRE   + (64+j)*64 + d] * re[j];
    }
    ws[OFF_RELC + i] = s1;
    ws[OFF_RELR + i] = s2;
    return;
  }
  int gid = (bid - 17)*256 + threadIdx.x;   // 65536 threads
  int b = gid >> 6, lane = gid & 63;
  long ui = uidx[b];
  float ugd = user_emb[ui*64 + lane];
  ws[OFF_USERG + b*64 + lane] = ugd;
  const float* WtT = ws + OFF_WTATT;
  float acc = b_tatt[lane];
  for (int j = 0; j < 64; ++j) acc += WtT[j*64 + lane] * __shfl(ugd, j);
  ws[OFF_UATT + b*64 + lane] = fmaxf(acc, 0.f);
}

// GRU MAC macros (s_load weights via uniform restrict ptr, v_pk_fma pairs)
#define GACC(AR_, AZ_, AN_, WP_, XS_) { \
  v2f xx_; xx_.x = (XS_); xx_.y = (XS_); \
  AR_[0] += (*(const v2f*)((WP_)+ 0))*xx_; AR_[1] += (*(const v2f*)((WP_)+ 2))*xx_; \
  AR_[2] += (*(const v2f*)((WP_)+ 4))*xx_; AR_[3] += (*(const v2f*)((WP_)+ 6))*xx_; \
  AZ_[0] += (*(const v2f*)((WP_)+ 8))*xx_; AZ_[1] += (*(const v2f*)((WP_)+10))*xx_; \
  AZ_[2] += (*(const v2f*)((WP_)+12))*xx_; AZ_[3] += (*(const v2f*)((WP_)+14))*xx_; \
  AN_[0] += (*(const v2f*)((WP_)+16))*xx_; AN_[1] += (*(const v2f*)((WP_)+18))*xx_; \
  AN_[2] += (*(const v2f*)((WP_)+20))*xx_; AN_[3] += (*(const v2f*)((WP_)+22))*xx_; }

#define AGACC(AG_, WP_, XS_) { \
  v2f xx_; xx_.x = (XS_); xx_.y = (XS_); \
  AG_[0] += (*(const v2f*)((WP_)+0))*xx_; AG_[1] += (*(const v2f*)((WP_)+2))*xx_; \
  AG_[2] += (*(const v2f*)((WP_)+4))*xx_; AG_[3] += (*(const v2f*)((WP_)+6))*xx_; }

// ---------------- FUSED gru+agg+kg kernel (round-10) ----------------
// Round-9 post-mortem: fused 411us (VALU 201us); kg (~60-70us, fully independent of
// fused's outputs) still ran serially in fused2. KGS relocated to the dead ULCPN
// region -> no overlay hazard with the GRU packs -> kg joins fused as block type 3
// (bid>=1632), backfilling gru/agg drain slots. Block order: gru (critical path,
// 0..543) -> agg (544..1631) -> kg (1632..1887).
__global__ __launch_bounds__(512, 4) void fused_kernel(
  const int* __restrict__ ghS, const int* __restrict__ ghP,
  const int* __restrict__ gpS, const int* __restrict__ gpP,
  const int* __restrict__ gnS, const int* __restrict__ gnP,
  const float* __restrict__ b_ih, const float* __restrict__ b_hh,
  const float* __restrict__ WIHP, const float* __restrict__ WHHP,
  const float* __restrict__ WAGP,
  float* __restrict__ outHis, float* __restrict__ outPN,
  const int* __restrict__ ahS, const int* __restrict__ ahN, const int* __restrict__ ahR,
  const int* __restrict__ apS, const int* __restrict__ apN, const int* __restrict__ apR,
  const int* __restrict__ anS, const int* __restrict__ anN, const int* __restrict__ anR,
  const float* __restrict__ b_gatt, const float* __restrict__ b_agg,
  const int* __restrict__ kh, const int* __restrict__ kr,
  const int* __restrict__ kt, const int* __restrict__ ktn,
  const float* __restrict__ entity, float* __restrict__ ws)
{
  __shared__ float SH[8320];                // 33,280 B: gru = hb|xb, agg = WL(8192), kg = WL(4096)
  int tid = threadIdx.x;
  int bid = blockIdx.x;

  if (bid < NGRU){
    // ================= GRU path (blocks 0..543, start first) =================
    int rep = bid;
    float (*hb)[65] = (float(*)[65])SH;
    float (*xb)[65] = (float(*)[65])(SH + 4160);
    int w = __builtin_amdgcn_readfirstlane(tid >> 6);
    int lane = tid & 63;
    int rbase = rep*64;
    const int *sIv, *pIv; float* aO; int nb0;
    if (rbase < NH)          { sIv=ghS; pIv=ghP; aO=outHis;       nb0=rbase; }
    else if (rbase < NH+Bb)  { sIv=gpS; pIv=gpP; aO=outPN;        nb0=rbase-NH; }
    else                     { sIv=gnS; pIv=gnP; aO=outPN+65536;  nb0=rbase-NH-Bb; }
    int o0 = w*8;
    int nrow = nb0 + lane;

    int pt = pIv[nrow*8];
    int pt_next = pIv[nrow*8 + 1];
    {
      const float* ex = entity + (long)pt*64 + o0;
      float4 xa0 = ld4(ex), xc0 = ld4(ex + 4);
      st4(&xb[lane][o0], xa0);
      st4(&xb[lane][o0+4], xc0);
    }
    __syncthreads();

    #pragma unroll 1
    for (int t = 0; t < 8; ++t){
      float4 xa = {0,0,0,0}, xc = {0,0,0,0};
      if (t < 7){
        const float* ex = entity + (long)pt_next*64 + o0;
        xa = ld4(ex); xc = ld4(ex + 4);
        if (t < 6) pt_next = pIv[nrow*8 + t + 2];
      }
      v2f ar[4], az[4], ah[4];
      #pragma unroll
      for (int p = 0; p < 4; ++p){
        ar[p].x = b_ih[o0+2*p]      + b_hh[o0+2*p];
        ar[p].y = b_ih[o0+2*p+1]    + b_hh[o0+2*p+1];
        az[p].x = b_ih[64+o0+2*p]   + b_hh[64+o0+2*p];
        az[p].y = b_ih[64+o0+2*p+1] + b_hh[64+o0+2*p+1];
        ah[p].x = b_hh[128+o0+2*p];   ah[p].y = b_hh[128+o0+2*p+1];
      }
      if (t){
        #pragma unroll 2
        for (int jc = 0; jc < 16; ++jc){
          const float* wp = WHHP + (jc*8 + w)*96;
          float4 h4 = ld4(&hb[lane][4*jc]);
          GACC(ar, az, ah, wp,      h4.x);
          GACC(ar, az, ah, wp + 24, h4.y);
          GACC(ar, az, ah, wp + 48, h4.z);
          GACC(ar, az, ah, wp + 72, h4.w);
        }
      }
      v2f an[4];
      #pragma unroll
      for (int p = 0; p < 4; ++p){ an[p].x = b_ih[128+o0+2*p]; an[p].y = b_ih[128+o0+2*p+1]; }
      #pragma unroll 2
      for (int jc = 0; jc < 16; ++jc){
        const float* wp = WIHP + (jc*8 + w)*96;
        float4 x4 = ld4(&xb[lane][4*jc]);
        GACC(ar, az, an, wp,      x4.x);
        GACC(ar, az, an, wp + 24, x4.y);
        GACC(ar, az, an, wp + 48, x4.z);
        GACC(ar, az, an, wp + 72, x4.w);
      }
      float hp[8] = {0,0,0,0,0,0,0,0};
      if (t){
        float4 hv0 = ld4(&hb[lane][o0]); float4 hv1 = ld4(&hb[lane][o0+4]);
        hp[0]=hv0.x; hp[1]=hv0.y; hp[2]=hv0.z; hp[3]=hv0.w;
        hp[4]=hv1.x; hp[5]=hv1.y; hp[6]=hv1.z; hp[7]=hv1.w;
      }
      float hn[8];
      #pragma unroll
      for (int p = 0; p < 4; ++p){
        float r0 = sigmoid_fast(ar[p].x), r1 = sigmoid_fast(ar[p].y);
        float z0 = sigmoid_fast(az[p].x), z1 = sigmoid_fast(az[p].y);
        float n0 = tanh_fast(an[p].x + r0*ah[p].x);
        float n1 = tanh_fast(an[p].y + r1*ah[p].y);
        hn[2*p]   = (1.f - z0)*n0 + z0*hp[2*p];
        hn[2*p+1] = (1.f - z1)*n1 + z1*hp[2*p+1];
      }
      __syncthreads();                      // C
      float4 s0 = {hn[0],hn[1],hn[2],hn[3]}, s1 = {hn[4],hn[5],hn[6],hn[7]};
      st4(&hb[lane][o0], s0);
      st4(&hb[lane][o0+4], s1);
      if (t < 7){
        st4(&xb[lane][o0], xa);
        st4(&xb[lane][o0+4], xc);
      }
      __syncthreads();                      // D
    }

    long si = sIv[nrow];
    const float* es = entity + si*64 + o0;
    float4 aa = ld4(es), cc = ld4(es + 4);
    v2f ag[4];
    #pragma unroll
    for (int p = 0; p < 4; ++p){ ag[p].x = b_agg[o0+2*p]; ag[p].y = b_agg[o0+2*p+1]; }
    #pragma unroll 2
    for (int jc = 0; jc < 16; ++jc){
      const float* wp = WAGP + ((16+jc)*8 + w)*32;
      float4 h4 = ld4(&hb[lane][4*jc]);
      AGACC(ag, wp,      h4.x);
      AGACC(ag, wp + 8,  h4.y);
      AGACC(ag, wp + 16, h4.z);
      AGACC(ag, wp + 24, h4.w);
    }
    st4(&xb[lane][o0], aa);
    st4(&xb[lane][o0+4], cc);
    __syncthreads();                        // E
    #pragma unroll 2
    for (int jc = 0; jc < 16; ++jc){
      const float* wp = WAGP + (jc*8 + w)*32;
      float4 x4 = ld4(&xb[lane][4*jc]);
      AGACC(ag, wp,      x4.x);
      AGACC(ag, wp + 8,  x4.y);
      AGACC(ag, wp + 16, x4.z);
      AGACC(ag, wp + 24, x4.w);
    }
    {
      float4 s0 = {tanh_fast(ag[0].x), tanh_fast(ag[0].y), tanh_fast(ag[1].x), tanh_fast(ag[1].y)};
      float4 s1 = {tanh_fast(ag[2].x), tanh_fast(ag[2].y), tanh_fast(ag[3].x), tanh_fast(ag[3].y)};
      st4(&hb[lane][o0], s0);
      st4(&hb[lane][o0+4], s1);
    }
    __syncthreads();                        // F
    int q = tid & 7, r = tid >> 3;
    float4 v0 = ld4(&hb[r][q*8]);
    float4 v1 = ld4(&hb[r][q*8+4]);
    float ss = v0.x*v0.x + v0.y*v0.y + v0.z*v0.z + v0.w*v0.w
             + v1.x*v1.x + v1.y*v1.y + v1.z*v1.z + v1.w*v1.w;
    ss += __shfl_xor(ss, 1); ss += __shfl_xor(ss, 2); ss += __shfl_xor(ss, 4);
    float rn = __fdividef(1.f, fmaxf(sqrtf(ss), 1e-12f));
    int n2 = nb0 + r;
    float4 o4a = {v0.x*rn, v0.y*rn, v0.z*rn, v0.w*rn};
    float4 o4b = {v1.x*rn, v1.y*rn, v1.z*rn, v1.w*rn};
    st4(aO + (long)n2*64 + q*8,     o4a);
    st4(aO + (long)n2*64 + q*8 + 4, o4b);
    return;
  }

  if (bid < NGRU + NAGG){
    // ================= AGG path (blocks 544..1631) =================
    float* WL = SH;
    int ablk = bid - NGRU;                  // 0..1087
    int tid2 = tid & 255;
    int sub  = tid >> 8;
    int k = tid2 & 15, rl = tid2 >> 4;
    int rbase = ablk*32;
    const int *sI, *nI, *rI; float *sO, *aO; int nb0, uhis;
    if (rbase < NH)          { sI=ahS; nI=ahN; rI=ahR; sO=ws+OFF_SELFH;        aO=ws+OFF_HISLC;       nb0=rbase;        uhis=1; }
    else if (rbase < NH+Bb)  { sI=apS; nI=apN; rI=apR; sO=ws+OFF_SELFPN;       aO=ws+OFF_LCPN;       nb0=rbase-NH;     uhis=0; }
    else                     { sI=anS; nI=anN; rI=anR; sO=ws+OFF_SELFPN+65536; aO=ws+OFF_LCPN+65536; nb0=rbase-NH-Bb;  uhis=0; }
    int n = nb0 + sub*16 + rl;
    int urow = uhis ? (n >> 5) : n;

    for (int i = tid; i < 1024; i += 512){
      st4(&WL[4*i],        ld4(ws + OFF_WCOMB + 4*i));
      st4(&WL[4096 + 4*i], ld4(ws + OFF_WGS   + 4*i));
    }

    const float* es = entity + (long)sI[n]*64;
    long nbI = nI[n*16 + k], rlI = rI[n*16 + k];
    const float* en = entity + nbI*64;

    v2f acc2[32];
    {
      const float* rt = ws + OFF_RELC + rlI*64;
      #pragma unroll
      for (int j4 = 0; j4 < 16; ++j4){
        float4 v = ld4(rt + 4*j4);
        acc2[2*j4]   = (v2f){v.x, v.y};
        acc2[2*j4+1] = (v2f){v.z, v.w};
      }
    }
    __syncthreads();

    float4 sc4 = ld4(b_gatt + k*4);
    #pragma unroll 2
    for (int j4 = 0; j4 < 16; ++j4){
      float4 s4 = ld4(es + 4*j4);
      float4 w0 = *(const float4*)&WL[4096 + (4*j4+0)*64 + k*4];
      float4 w1 = *(const float4*)&WL[4096 + (4*j4+1)*64 + k*4];
      float4 w2 = *(const float4*)&WL[4096 + (4*j4+2)*64 + k*4];
      float4 w3 = *(const float4*)&WL[4096 + (4*j4+3)*64 + k*4];
      sc4.x += w0.x*s4.x + w1.x*s4.y + w2.x*s4.z + w3.x*s4.w;
      sc4.y += w0.y*s4.x + w1.y*s4.y + w2.y*s4.z + w3.y*s4.w;
      sc4.z += w0.z*s4.x + w1.z*s4.y + w2.z*s4.z + w3.z*s4.w;
      sc4.w += w0.w*s4.x + w1.w*s4.y + w2.w*s4.z + w3.w*s4.w;
    }
    st4(sO + (long)n*64 + k*4, ld4(es + k*4));

    {
      float4 x4 = ld4(en);
      #pragma unroll 2
      for (int j4 = 0; j4 < 16; ++j4){
        float4 xn = ld4(en + 4*((j4+1) & 15));
        v2f xx0; xx0.x = x4.x; xx0.y = x4.x;
        MVJ2(acc2, &WL[(4*j4+0)*64], xx0);
        v2f xx1; xx1.x = x4.y; xx1.y = x4.y;
        MVJ2(acc2, &WL[(4*j4+1)*64], xx1);
        v2f xx2; xx2.x = x4.z; xx2.y = x4.z;
        MVJ2(acc2, &WL[(4*j4+2)*64], xx2);
        v2f xx3; xx3.x = x4.w; xx3.y = x4.w;
        MVJ2(acc2, &WL[(4*j4+3)*64], xx3);
        x4 = xn;
      }
    }

    int gl = (tid & 63) & 48;
    const float* up = ws + OFF_UATT + (long)urow*64;
    float lg = 0.f;
    #pragma unroll
    for (int j4 = 0; j4 < 16; ++j4){
      float4 u4 = ld4(up + 4*j4);
      float s0 = __shfl(sc4.x, gl + j4);
      float s1 = __shfl(sc4.y, gl + j4);
      float s2 = __shfl(sc4.z, gl + j4);
      float s3 = __shfl(sc4.w, gl + j4);
      lg += u4.x*tanh_fast(acc2[2*j4].x   + s0);
      lg += u4.y*tanh_fast(acc2[2*j4].y   + s1);
      lg += u4.z*tanh_fast(acc2[2*j4+1].x + s2);
      lg += u4.w*tanh_fast(acc2[2*j4+1].y + s3);
    }
    float mx = lg;
    mx = fmaxf(mx, __shfl_xor(mx, 1)); mx = fmaxf(mx, __shfl_xor(mx, 2));
    mx = fmaxf(mx, __shfl_xor(mx, 4)); mx = fmaxf(mx, __shfl_xor(mx, 8));
    float e = __expf(lg - mx);
    float se = e;
    se += __shfl_xor(se, 1); se += __shfl_xor(se, 2);
    se += __shfl_xor(se, 4); se += __shfl_xor(se, 8);
    float att = __fdividef(e, se);

    __syncthreads();
    for (int i = tid; i < 2048; i += 512)
      st4(&WL[4*i], ld4(ws + OFF_WAGG + 4*i));
    __syncthreads();

    float4 a4 = ld4(b_agg + k*4);
    #pragma unroll 2
    for (int j4 = 0; j4 < 16; ++j4){
      float4 s4 = ld4(es + 4*j4);
      float4 w0 = *(const float4*)&WL[(4*j4+0)*64 + k*4];
      float4 w1 = *(const float4*)&WL[(4*j4+1)*64 + k*4];
      float4 w2 = *(const float4*)&WL[(4*j4+2)*64 + k*4];
      float4 w3 = *(const float4*)&WL[(4*j4+3)*64 + k*4];
      a4.x += w0.x*s4.x + w1.x*s4.y + w2.x*s4.z + w3.x*s4.w;
      a4.y += w0.y*s4.x + w1.y*s4.y + w2.y*s4.z + w3.y*s4.w;
      a4.z += w0.z*s4.x + w1.z*s4.y + w2.z*s4.z + w3.z*s4.w;
      a4.w += w0.w*s4.x + w1.w*s4.y + w2.w*s4.z + w3.w*s4.w;
    }
    #pragma unroll 2
    for (int j4 = 0; j4 < 16; ++j4){
      float4 x4 = ld4(en + 4*j4);
      float xs[4] = {x4.x, x4.y, x4.z, x4.w};
      #pragma unroll
      for (int jj = 0; jj < 4; ++jj){
        float v = att * xs[jj];
        v += __shfl_xor(v, 1); v += __shfl_xor(v, 2);
        v += __shfl_xor(v, 4); v += __shfl_xor(v, 8);
        float4 wv = *(const float4*)&WL[(64 + 4*j4 + jj)*64 + k*4];
        a4.x += wv.x*v; a4.y += wv.y*v; a4.z += wv.z*v; a4.w += wv.w*v;
      }
    }
    float t0 = tanh_fast(a4.x), t1 = tanh_fast(a4.y), t2 = tanh_fast(a4.z), t3 = tanh_fast(a4.w);
    float ss = t0*t0 + t1*t1 + t2*t2 + t3*t3;
    ss += __shfl_xor(ss, 1); ss += __shfl_xor(ss, 2);
    ss += __shfl_xor(ss, 4); ss += __shfl_xor(ss, 8);
    float rn = __fdividef(1.f, fmaxf(sqrtf(ss), 1e-12f));
    float4 o4; o4.x = t0*rn; o4.y = t1*rn; o4.z = t2*rn; o4.w = t3*rn;
    st4(aO + (long)n*64 + k*4, o4);
    return;
  }

  // ================= KG path (blocks 1632..1887; one thread per (r,branch)) =================
  {
    float* WL = SH;
    int rep = bid - NGRU - NAGG;            // 0..255
    int idx = rep*512 + tid;                // 0..131071
    int br = idx >> 16, r = idx & 65535;
    const int* tailI = br ? ktn : kt;
    for (int i = tid; i < 1024; i += 512)
      st4(&WL[4*i], ld4(ws + OFF_WRE + 4*i));

    long rel = kr[r];
    const float* et = entity + (long)tailI[r]*64;
    v2f acc2[32];
    {
      const float* rt = ws + OFF_RELR + rel*64;
      #pragma unroll
      for (int j4 = 0; j4 < 16; ++j4){
        float4 v = ld4(rt + 4*j4);
        acc2[2*j4]   = (v2f){v.x, v.y};
        acc2[2*j4+1] = (v2f){v.z, v.w};
      }
    }
    __syncthreads();
    {
      float4 x4 = ld4(et);
      #pragma unroll 2
      for (int j4 = 0; j4 < 16; ++j4){
        float4 xn = ld4(et + 4*((j4+1) & 15));
        v2f xx0; xx0.x = x4.x; xx0.y = x4.x;
        MVJ2(acc2, &WL[(4*j4+0)*64], xx0);
        v2f xx1; xx1.x = x4.y; xx1.y = x4.y;
        MVJ2(acc2, &WL[(4*j4+1)*64], xx1);
        v2f xx2; xx2.x = x4.z; xx2.y = x4.z;
        MVJ2(acc2, &WL[(4*j4+2)*64], xx2);
        v2f xx3; xx3.x = x4.w; xx3.y = x4.w;
        MVJ2(acc2, &WL[(4*j4+3)*64], xx3);
        x4 = xn;
      }
    }
    const float* eh = entity + (long)kh[r]*64;
    float s = 0.f;
    #pragma unroll
    for (int j4 = 0; j4 < 16; ++j4){
      float4 h4 = ld4(eh + 4*j4);
      float d0 = h4.x - acc2[2*j4].x,   d1 = h4.y - acc2[2*j4].y;
      float d2 = h4.z - acc2[2*j4+1].x, d3 = h4.w - acc2[2*j4+1].y;
      s += d0*d0 + d1*d1 + d2*d2 + d3*d3;
    }
    ws[OFF_KGS + br*65536 + r] = s;
  }
}

// ---------------- FUSED2: rs (bid<256) + kg_reduce (bid>=256) ----------------
__global__ __launch_bounds__(512, 4) void fused2_kernel(
  const float* __restrict__ W_iatt, const float* __restrict__ b_iatt,
  const float* __restrict__ b_u,
  float* __restrict__ ws, float* __restrict__ out)
{
  int tid = threadIdx.x;
  int bid = blockIdx.x;

  if (bid >= 256){
    // ---- kg_reduce path (128 blocks x 512) ----
    int r = (bid - 256)*512 + tid;          // 0..65535
    float s  = ws[OFF_KGS + r];
    float sn = ws[OFF_KGS + 65536 + r];
    float dif = sn - s;
    float ls = fminf(dif, 0.f) - __logf(1.f + __expf(-fabsf(dif)));
    #pragma unroll
    for (int m2 = 1; m2 < 64; m2 <<= 1) ls += __shfl_xor(ls, m2);
    if ((tid & 63) == 0) atomicAdd(ws + OFF_KGSUM, ls);
    return;
  }

  // ---- RSATT+UMLP path (256 blocks, one wave per (b,branch)) ----
  int gw = bid*8 + (tid >> 6), lane = tid & 63;
  int b = gw >> 1, br = gw & 1;
  const float* selfB = ws + OFF_SELFPN + br*65536 + b*64;
  const float* lcB   = ws + OFF_LCPN   + br*65536 + b*64;
  const float* gbB   = ws + OFF_GBPN   + br*65536 + b*64;
  const float* gvec  = ws + OFF_GVEC;
  const float* selfH = ws + OFF_SELFH;
  const float* hisLC = ws + OFF_HISLC;
  const float* hisGB = ws + OFF_HISGB;

  float gd = gvec[lane];
  float ugd = ws[OFF_USERG + b*64 + lane];
  float sv = selfB[lane], lcv = lcB[lane], gbv = gbB[lane];
  float gated = gd*lcv + (1.f - gd)*gbv;
  float part = W_iatt[128+lane]*sv + W_iatt[192+lane]*gated;
  #pragma unroll
  for (int m2 = 1; m2 < 64; m2 <<= 1) part += __shfl_xor(part, m2);
  float itemdot = part + b_iatt[0];

  int m = lane & 31, half = lane >> 5;
  long nrow = (long)(b*32 + m)*64;
  float sh = 0.f;
  if (half == 0){
    for (int j4 = 0; j4 < 16; ++j4){
      float4 h4 = ld4(selfH + nrow + 4*j4);
      float4 w4 = ld4(W_iatt + 4*j4);
      sh += w4.x*h4.x + w4.y*h4.y + w4.z*h4.z + w4.w*h4.w;
    }
  } else {
    for (int j4 = 0; j4 < 16; ++j4){
      float4 l4 = ld4(hisLC + nrow + 4*j4);
      float4 g4 = ld4(hisGB + nrow + 4*j4);
      float4 gg = ld4(gvec + 4*j4);
      float4 w4 = ld4(W_iatt + 64 + 4*j4);
      sh += w4.x*(gg.x*l4.x + (1.f-gg.x)*g4.x);
      sh += w4.y*(gg.y*l4.y + (1.f-gg.y)*g4.y);
      sh += w4.z*(gg.z*l4.z + (1.f-gg.z)*g4.z);
      sh += w4.w*(gg.w*l4.w + (1.f-gg.w)*g4.w);
    }
  }
  sh += __shfl_xor(sh, 32);
  float logit = tanh_fast(sh + itemdot);
  float mxv = logit;
  #pragma unroll
  for (int m2 = 1; m2 < 32; m2 <<= 1) mxv = fmaxf(mxv, __shfl_xor(mxv, m2));
  float e = __expf(logit - mxv);
  float se = e;
  #pragma unroll
  for (int m2 = 1; m2 < 32; m2 <<= 1) se += __shfl_xor(se, m2);
  float att = __fdividef(e, se);

  float u1 = 0.f, u2 = 0.f;
  for (int mm = 0; mm < 32; ++mm){
    float a = __shfl(att, mm);
    long nr = (long)(b*32 + mm)*64;
    float x1 = selfH[nr + lane];
    float x2 = gd*hisLC[nr + lane] + (1.f - gd)*hisGB[nr + lane];
    u1 += a*x1; u2 += a*x2;
  }

  const float* WuT = ws + OFF_WU;
  float acc = b_u[lane];
  for (int j = 0; j < 64; ++j) acc += WuT[j*64 + lane]        * __shfl(ugd, j);
  for (int j = 0; j < 64; ++j) acc += WuT[(64 + j)*64 + lane] * __shfl(u1, j);
  for (int j = 0; j < 64; ++j) acc += WuT[(128 + j)*64 + lane]* __shfl(u2, j);
  float uo = fmaxf(acc, 0.f);
  float ssv = uo*uo;
  #pragma unroll
  for (int m2 = 1; m2 < 64; m2 <<= 1) ssv += __shfl_xor(ssv, m2);
  float rn = __fdividef(1.f, fmaxf(sqrtf(ssv), 1e-12f));
  float nuo = uo*rn;
  float p = ugd*sv + nuo*gated;
  #pragma unroll
  for (int m2 = 1; m2 < 64; m2 <<= 1) p += __shfl_xor(p, m2);
  if (lane == 0) out[br*1024 + b] = p;
}

// ---------------- final loss ----------------
__global__ void loss_kernel(const float* __restrict__ ws, float* __restrict__ out)
{
  __shared__ float red[16];
  int t = threadIdx.x;
  float ps = out[t], ns_ = out[1024 + t];
  float dif = ps - ns_;
  float v = fminf(dif, 0.f) - __logf(1.f + __expf(-fabsf(dif)));
  #pragma unroll
  for (int m2 = 1; m2 < 64; m2 <<= 1) v += __shfl_xor(v, m2);
  if ((t & 63) == 0) red[t >> 6] = v;
  __syncthreads();
  if (t == 0){
    float s = 0.f;
    for (int i = 0; i < 16; ++i) s += red[i];
    float rs = -s * (1.f/1024.f);
    float kg = -ws[OFF_KGSUM] * (1.f/65536.f);
    out[2048] = rs + kg;
  }
}

extern "C" void kernel_launch(void* const* d_in, const int* in_sizes, int n_in,
                              void* d_out, int out_size, void* d_ws, size_t ws_size,
                              hipStream_t stream)
{
  const int* user_indices = (const int*)d_in[0];
  const int* ent_his_self = (const int*)d_in[1];
  const int* ent_his_nbr  = (const int*)d_in[2];
  const int* rel_his      = (const int*)d_in[3];
  const int* ent_pos_self = (const int*)d_in[4];
  const int* ent_pos_nbr  = (const int*)d_in[5];
  const int* rel_pos      = (const int*)d_in[6];
  const int* ent_neg_self = (const int*)d_in[7];
  const int* ent_neg_nbr  = (const int*)d_in[8];
  const int* rel_neg      = (const int*)d_in[9];
  const int* gb_his_self  = (const int*)d_in[10];
  const int* gb_his_path  = (const int*)d_in[11];
  const int* gb_pos_self  = (const int*)d_in[12];
  const int* gb_pos_path  = (const int*)d_in[13];
  const int* gb_neg_self  = (const int*)d_in[14];
  const int* gb_neg_path  = (const int*)d_in[15];
  const int* kg_head      = (const int*)d_in[16];
  const int* kg_rel       = (const int*)d_in[17];
  const int* kg_tail      = (const int*)d_in[18];
  const int* kg_tail_neg  = (const int*)d_in[19];
  const float* entity_emb   = (const float*)d_in[20];
  const float* relation_emb = (const float*)d_in[21];
  const float* user_emb     = (const float*)d_in[22];
  const float* gate         = (const float*)d_in[23];
  const float* W_u_mlp      = (const float*)d_in[24];
  const float* b_u_mlp      = (const float*)d_in[25];
  const float* W_re         = (const float*)d_in[26];
  const float* W_agg        = (const float*)d_in[27];
  const float* b_agg        = (const float*)d_in[28];
  const float* W_gatt       = (const float*)d_in[29];
  const float* b_gatt       = (const float*)d_in[30];
  const float* W_iatt       = (const float*)d_in[31];
  const float* b_iatt       = (const float*)d_in[32];
  const float* W_tatt       = (const float*)d_in[33];
  const float* b_tatt       = (const float*)d_in[34];
  const float* W_ih         = (const float*)d_in[35];
  const float* W_hh         = (const float*)d_in[36];
  const float* b_ih         = (const float*)d_in[37];
  const float* b_hh         = (const float*)d_in[38];
  float* ws  = (float*)d_ws;
  float* out = (float*)d_out;

  (void)hipMemsetAsync(ws + OFF_KGSUM, 0, sizeof(float), stream);
  prep1_kernel<<<32, 256, 0, stream>>>(W_tatt, W_gatt, W_re, W_agg, W_u_mlp, W_ih, W_hh, gate, ws);
  prep2_kernel<<<273, 256, 0, stream>>>(relation_emb, user_indices, user_emb, b_tatt, ws);
  // fused gru+agg+kg: gru 0..543 (critical path first), agg 544..1631, kg 1632..1887
  fused_kernel<<<NGRU + NAGG + NKGB, 512, 0, stream>>>(
      gb_his_self, gb_his_path, gb_pos_self, gb_pos_path,
      gb_neg_self, gb_neg_path,
      b_ih, b_hh,
      ws + OFF_WIHP, ws + OFF_WHHP, ws + OFF_WAGP,
      ws + OFF_HISGB, ws + OFF_GBPN,
      ent_his_self, ent_his_nbr, rel_his,
      ent_pos_self, ent_pos_nbr, rel_pos,
      ent_neg_self, ent_neg_nbr, rel_neg,
      b_gatt, b_agg,
      kg_head, kg_rel, kg_tail, kg_tail_neg,
      entity_emb, ws);
  // fused2: rs (256 blocks) + kg_reduce (128 blocks)
  fused2_kernel<<<384, 512, 0, stream>>>(W_iatt, b_iatt, b_u_mlp, ws, out);
  loss_kernel<<<1, 1024, 0, stream>>>(ws, out);
}

// Round 11
// 598.755 us; speedup vs baseline: 1.0295x; 1.0295x over previous
//
#include <hip/hip_runtime.h>

#define DEV __device__ __forceinline__

#define Dd   64
#define Bb   1024
#define Mm   32
#define Kk   16
#define Ll   8
#define NKGk 65536
#define NH   32768            // B*M
#define ROWS (NH + 2*Bb)      // 34816
#define NGRU (ROWS/64)        // 544 gru blocks
#define NAGG (ROWS/32)        // 1088 agg blocks

typedef float v2f __attribute__((ext_vector_type(2)));

// ---- workspace layout (float offsets) ----
#define OFF_WTATT   0          // 64x64  transposed W_tatt
#define OFF_WGS     4096       // 64x64  transposed W_gatt[:, :64]
#define OFF_WCOMB   8192       // 128x64 transposed (W_gatt[:,64:] @ W_re)
#define OFF_WRE     16384      // 128x64 transposed W_re
#define OFF_WAGG    24576      // 128x64 transposed W_agg
#define OFF_WU      32768      // 192x64 transposed W_u_mlp
#define OFF_GVEC    45056      // 64     sigmoid(gate)
#define OFF_USERG   45120      // 1024x64
#define OFF_UATT    110656     // 1024x64
#define OFF_SELFH   176192     // 32768x64
#define OFF_HISLC   2273344    // 32768x64
#define OFF_HISGB   4370496    // 32768x64
#define OFF_SELFPN  6467648    // 2x1024x64 (pos, then neg)
#define OFF_LCPN    6598720    // 2x1024x64
#define OFF_GBPN    6729792    // 2x1024x64
// KGS lives in the dead ULCPN region (unused since round-8 rsatt+umlp fusion):
// no overlap with the GRU weight packs, so ordering hazards are gone entirely.
#define OFF_KGS     6860864    // 2x65536 kg squared distances -> ends 6992000
#define OFF_KGSUM   7123008    // 1
#define OFF_WIHP    7123072    // 16x8x(4x3x8) = 12288  W_ih packed [jc][w][jj][gate][oi]
#define OFF_WHHP    7135360    // 12288                 W_hh packed
#define OFF_WAGP    7147648    // 32x8x(4x8)   = 8192   W_agg packed [jc][w][jj][oi]
#define OFF_RELC    7155840    // 65x64  (Wcomb_hi @ rel_emb[r])
#define OFF_RELR    7160000    // 65x64  (Wre_hi   @ rel_emb[r])

DEV float4 ld4(const float* p){ return *reinterpret_cast<const float4*>(p); }
DEV void st4(float* p, const float4 v){ *reinterpret_cast<float4*>(p) = v; }

DEV float tanh_fast(float x){
  float cx = fminf(15.f, fmaxf(-15.f, x));
  float e = __expf(2.f*cx);
  return __fdividef(e - 1.f, e + 1.f);
}
DEV float sigmoid_fast(float x){ return __fdividef(1.f, 1.f + __expf(-x)); }

// pk_fma matvec step: acc2[32] v2f pairs
#define MVJ2(ACC2_, WROW_, XX_) { \
  _Pragma("unroll") for (int d4_ = 0; d4_ < 16; ++d4_){ \
    float4 w_ = *(const float4*)((WROW_) + 4*d4_); \
    ACC2_[2*d4_]   += (v2f){w_.x, w_.y}*(XX_); \
    ACC2_[2*d4_+1] += (v2f){w_.z, w_.w}*(XX_); } }

// 4-output pk step: OUT2_[2] v2f accumulators, W4_ float4 of 4 consecutive outputs
#define PK4(OUT2_, W4_, XS_) { \
  v2f xx_; xx_.x = (XS_); xx_.y = (XS_); \
  OUT2_[0] += (v2f){(W4_).x, (W4_).y}*xx_; \
  OUT2_[1] += (v2f){(W4_).z, (W4_).w}*xx_; }

// ---------------- prep1: transposes + packs + gate (32 blocks) ----------------
__global__ void prep1_kernel(const float* __restrict__ W_tatt, const float* __restrict__ W_gatt,
                             const float* __restrict__ W_re, const float* __restrict__ W_agg,
                             const float* __restrict__ W_u, const float* __restrict__ W_ih,
                             const float* __restrict__ W_hh, const float* __restrict__ gate,
                             float* __restrict__ ws)
{
  int g = blockIdx.x*256 + threadIdx.x;     // 0..8191
  for (int i = g; i < 4096; i += 8192){
    int d = i >> 6, j = i & 63;
    ws[OFF_WTATT + j*64 + d] = W_tatt[i];
    ws[OFF_WGS   + j*64 + d] = W_gatt[d*128 + j];
  }
  for (int i = g; i < 8192; i += 8192){
    int j = i >> 6, d = i & 63;
    ws[OFF_WRE  + i] = W_re[d*128 + j];
    ws[OFF_WAGG + i] = W_agg[d*128 + j];
    float s = 0.f;
    for (int dp = 0; dp < 64; ++dp) s += W_gatt[d*128 + 64 + dp] * W_re[dp*128 + j];
    ws[OFF_WCOMB + i] = s;
  }
  for (int i = g; i < 12288; i += 8192){
    int j = i >> 6, d = i & 63;
    ws[OFF_WU + i] = W_u[d*192 + j];
  }
  for (int i = g; i < 12288; i += 8192){
    int jc = i / 768, r1 = i - jc*768;
    int ww = r1 / 96,  r2 = r1 - ww*96;
    int jj = r2 / 24,  r3 = r2 - jj*24;
    int gg = r3 >> 3,  oi = r3 & 7;
    int j = jc*4 + jj, o = gg*64 + ww*8 + oi;
    ws[OFF_WIHP + i] = W_ih[o*64 + j];
    ws[OFF_WHHP + i] = W_hh[o*64 + j];
  }
  for (int i = g; i < 8192; i += 8192){
    int jc = i >> 8, r1 = i & 255;
    int ww = r1 >> 5, r2 = r1 & 31;
    int jj = r2 >> 3, oi = r2 & 7;
    ws[OFF_WAGP + i] = W_agg[(ww*8 + oi)*128 + jc*4 + jj];
  }
  if (g < 64) ws[OFF_GVEC + g] = sigmoid_fast(gate[g]);
}

// ---------------- prep2: rel tables (bid<17) + user gather/u_att (bid>=17) ----------------
__global__ void prep2_kernel(const float* __restrict__ relation,
                             const int* __restrict__ uidx, const float* __restrict__ user_emb,
                             const float* __restrict__ b_tatt, float* __restrict__ ws)
{
  int bid = blockIdx.x;
  if (bid < 17){
    int i = bid*256 + threadIdx.x;          // 4352 >= 4160
    if (i >= 4160) return;
    int r = i >> 6, d = i & 63;
    const float* re = relation + r*64;
    float s1 = 0.f, s2 = 0.f;
    for (int j = 0; j < 64; ++j){
      s1 += ws[OFF_WCOMB + (64+j)*64 + d] * re[j];
      s2 += ws[OFF_WRE   + (64+j)*64 + d] * re[j];
    }
    ws[OFF_RELC + i] = s1;
    ws[OFF_RELR + i] = s2;
    return;
  }
  int gid = (bid - 17)*256 + threadIdx.x;   // 65536 threads
  int b = gid >> 6, lane = gid & 63;
  long ui = uidx[b];
  float ugd = user_emb[ui*64 + lane];
  ws[OFF_USERG + b*64 + lane] = ugd;
  const float* WtT = ws + OFF_WTATT;
  float acc = b_tatt[lane];
  for (int j = 0; j < 64; ++j) acc += WtT[j*64 + lane] * __shfl(ugd, j);
  ws[OFF_UATT + b*64 + lane] = fmaxf(acc, 0.f);
}

// GRU MAC macros (s_load weights via uniform restrict ptr, v_pk_fma pairs)
#define GACC(AR_, AZ_, AN_, WP_, XS_) { \
  v2f xx_; xx_.x = (XS_); xx_.y = (XS_); \
  AR_[0] += (*(const v2f*)((WP_)+ 0))*xx_; AR_[1] += (*(const v2f*)((WP_)+ 2))*xx_; \
  AR_[2] += (*(const v2f*)((WP_)+ 4))*xx_; AR_[3] += (*(const v2f*)((WP_)+ 6))*xx_; \
  AZ_[0] += (*(const v2f*)((WP_)+ 8))*xx_; AZ_[1] += (*(const v2f*)((WP_)+10))*xx_; \
  AZ_[2] += (*(const v2f*)((WP_)+12))*xx_; AZ_[3] += (*(const v2f*)((WP_)+14))*xx_; \
  AN_[0] += (*(const v2f*)((WP_)+16))*xx_; AN_[1] += (*(const v2f*)((WP_)+18))*xx_; \
  AN_[2] += (*(const v2f*)((WP_)+20))*xx_; AN_[3] += (*(const v2f*)((WP_)+22))*xx_; }

#define AGACC(AG_, WP_, XS_) { \
  v2f xx_; xx_.x = (XS_); xx_.y = (XS_); \
  AG_[0] += (*(const v2f*)((WP_)+0))*xx_; AG_[1] += (*(const v2f*)((WP_)+2))*xx_; \
  AG_[2] += (*(const v2f*)((WP_)+4))*xx_; AG_[3] += (*(const v2f*)((WP_)+6))*xx_; }

// ---------------- FUSED gru+agg kernel (round-11: kg REVERTED out; agg fully pk) ----------------
// Round-10 post-mortem: adding kg blocks thrashed L2 (WRITE 26->172MB: agg/gru outputs
// evicted to HBM and re-fetched by fused2) and gave ZERO overlap (fused +63us = kg's
// full serial cost). Reverted to the round-9 shape (598us). New here: the agg path's
// remaining scalar-FMA sections (sc matvec, W_agg self half, butterfly MAC) are
// pk_fma'd (~640 scalar FMA -> ~320 pk per agg thread).
__global__ __launch_bounds__(512, 4) void fused_kernel(
  const int* __restrict__ ghS, const int* __restrict__ ghP,
  const int* __restrict__ gpS, const int* __restrict__ gpP,
  const int* __restrict__ gnS, const int* __restrict__ gnP,
  const float* __restrict__ b_ih, const float* __restrict__ b_hh,
  const float* __restrict__ WIHP, const float* __restrict__ WHHP,
  const float* __restrict__ WAGP,
  float* __restrict__ outHis, float* __restrict__ outPN,
  const int* __restrict__ ahS, const int* __restrict__ ahN, const int* __restrict__ ahR,
  const int* __restrict__ apS, const int* __restrict__ apN, const int* __restrict__ apR,
  const int* __restrict__ anS, const int* __restrict__ anN, const int* __restrict__ anR,
  const float* __restrict__ b_gatt, const float* __restrict__ b_agg,
  const float* __restrict__ entity, float* __restrict__ ws)
{
  __shared__ float SH[8320];                // 33,280 B: gru = hb|xb, agg = WL
  int tid = threadIdx.x;
  int bid = blockIdx.x;

  if (bid < NGRU){
    // ================= GRU path (blocks 0..543, start first) =================
    int rep = bid;
    float (*hb)[65] = (float(*)[65])SH;
    float (*xb)[65] = (float(*)[65])(SH + 4160);
    int w = __builtin_amdgcn_readfirstlane(tid >> 6);
    int lane = tid & 63;
    int rbase = rep*64;
    const int *sIv, *pIv; float* aO; int nb0;
    if (rbase < NH)          { sIv=ghS; pIv=ghP; aO=outHis;       nb0=rbase; }
    else if (rbase < NH+Bb)  { sIv=gpS; pIv=gpP; aO=outPN;        nb0=rbase-NH; }
    else                     { sIv=gnS; pIv=gnP; aO=outPN+65536;  nb0=rbase-NH-Bb; }
    int o0 = w*8;
    int nrow = nb0 + lane;

    int pt = pIv[nrow*8];
    int pt_next = pIv[nrow*8 + 1];
    {
      const float* ex = entity + (long)pt*64 + o0;
      float4 xa0 = ld4(ex), xc0 = ld4(ex + 4);
      st4(&xb[lane][o0], xa0);
      st4(&xb[lane][o0+4], xc0);
    }
    __syncthreads();

    #pragma unroll 1
    for (int t = 0; t < 8; ++t){
      float4 xa = {0,0,0,0}, xc = {0,0,0,0};
      if (t < 7){
        const float* ex = entity + (long)pt_next*64 + o0;
        xa = ld4(ex); xc = ld4(ex + 4);
        if (t < 6) pt_next = pIv[nrow*8 + t + 2];
      }
      v2f ar[4], az[4], ah[4];
      #pragma unroll
      for (int p = 0; p < 4; ++p){
        ar[p].x = b_ih[o0+2*p]      + b_hh[o0+2*p];
        ar[p].y = b_ih[o0+2*p+1]    + b_hh[o0+2*p+1];
        az[p].x = b_ih[64+o0+2*p]   + b_hh[64+o0+2*p];
        az[p].y = b_ih[64+o0+2*p+1] + b_hh[64+o0+2*p+1];
        ah[p].x = b_hh[128+o0+2*p];   ah[p].y = b_hh[128+o0+2*p+1];
      }
      if (t){
        #pragma unroll 2
        for (int jc = 0; jc < 16; ++jc){
          const float* wp = WHHP + (jc*8 + w)*96;
          float4 h4 = ld4(&hb[lane][4*jc]);
          GACC(ar, az, ah, wp,      h4.x);
          GACC(ar, az, ah, wp + 24, h4.y);
          GACC(ar, az, ah, wp + 48, h4.z);
          GACC(ar, az, ah, wp + 72, h4.w);
        }
      }
      v2f an[4];
      #pragma unroll
      for (int p = 0; p < 4; ++p){ an[p].x = b_ih[128+o0+2*p]; an[p].y = b_ih[128+o0+2*p+1]; }
      #pragma unroll 2
      for (int jc = 0; jc < 16; ++jc){
        const float* wp = WIHP + (jc*8 + w)*96;
        float4 x4 = ld4(&xb[lane][4*jc]);
        GACC(ar, az, an, wp,      x4.x);
        GACC(ar, az, an, wp + 24, x4.y);
        GACC(ar, az, an, wp + 48, x4.z);
        GACC(ar, az, an, wp + 72, x4.w);
      }
      float hp[8] = {0,0,0,0,0,0,0,0};
      if (t){
        float4 hv0 = ld4(&hb[lane][o0]); float4 hv1 = ld4(&hb[lane][o0+4]);
        hp[0]=hv0.x; hp[1]=hv0.y; hp[2]=hv0.z; hp[3]=hv0.w;
        hp[4]=hv1.x; hp[5]=hv1.y; hp[6]=hv1.z; hp[7]=hv1.w;
      }
      float hn[8];
      #pragma unroll
      for (int p = 0; p < 4; ++p){
        float r0 = sigmoid_fast(ar[p].x), r1 = sigmoid_fast(ar[p].y);
        float z0 = sigmoid_fast(az[p].x), z1 = sigmoid_fast(az[p].y);
        float n0 = tanh_fast(an[p].x + r0*ah[p].x);
        float n1 = tanh_fast(an[p].y + r1*ah[p].y);
        hn[2*p]   = (1.f - z0)*n0 + z0*hp[2*p];
        hn[2*p+1] = (1.f - z1)*n1 + z1*hp[2*p+1];
      }
      __syncthreads();                      // C
      float4 s0 = {hn[0],hn[1],hn[2],hn[3]}, s1 = {hn[4],hn[5],hn[6],hn[7]};
      st4(&hb[lane][o0], s0);
      st4(&hb[lane][o0+4], s1);
      if (t < 7){
        st4(&xb[lane][o0], xa);
        st4(&xb[lane][o0+4], xc);
      }
      __syncthreads();                      // D
    }

    long si = sIv[nrow];
    const float* es = entity + si*64 + o0;
    float4 aa = ld4(es), cc = ld4(es + 4);
    v2f ag[4];
    #pragma unroll
    for (int p = 0; p < 4; ++p){ ag[p].x = b_agg[o0+2*p]; ag[p].y = b_agg[o0+2*p+1]; }
    #pragma unroll 2
    for (int jc = 0; jc < 16; ++jc){
      const float* wp = WAGP + ((16+jc)*8 + w)*32;
      float4 h4 = ld4(&hb[lane][4*jc]);
      AGACC(ag, wp,      h4.x);
      AGACC(ag, wp + 8,  h4.y);
      AGACC(ag, wp + 16, h4.z);
      AGACC(ag, wp + 24, h4.w);
    }
    st4(&xb[lane][o0], aa);
    st4(&xb[lane][o0+4], cc);
    __syncthreads();                        // E
    #pragma unroll 2
    for (int jc = 0; jc < 16; ++jc){
      const float* wp = WAGP + (jc*8 + w)*32;
      float4 x4 = ld4(&xb[lane][4*jc]);
      AGACC(ag, wp,      x4.x);
      AGACC(ag, wp + 8,  x4.y);
      AGACC(ag, wp + 16, x4.z);
      AGACC(ag, wp + 24, x4.w);
    }
    {
      float4 s0 = {tanh_fast(ag[0].x), tanh_fast(ag[0].y), tanh_fast(ag[1].x), tanh_fast(ag[1].y)};
      float4 s1 = {tanh_fast(ag[2].x), tanh_fast(ag[2].y), tanh_fast(ag[3].x), tanh_fast(ag[3].y)};
      st4(&hb[lane][o0], s0);
      st4(&hb[lane][o0+4], s1);
    }
    __syncthreads();                        // F
    int q = tid & 7, r = tid >> 3;
    float4 v0 = ld4(&hb[r][q*8]);
    float4 v1 = ld4(&hb[r][q*8+4]);
    float ss = v0.x*v0.x + v0.y*v0.y + v0.z*v0.z + v0.w*v0.w
             + v1.x*v1.x + v1.y*v1.y + v1.z*v1.z + v1.w*v1.w;
    ss += __shfl_xor(ss, 1); ss += __shfl_xor(ss, 2); ss += __shfl_xor(ss, 4);
    float rn = __fdividef(1.f, fmaxf(sqrtf(ss), 1e-12f));
    int n2 = nb0 + r;
    float4 o4a = {v0.x*rn, v0.y*rn, v0.z*rn, v0.w*rn};
    float4 o4b = {v1.x*rn, v1.y*rn, v1.z*rn, v1.w*rn};
    st4(aO + (long)n2*64 + q*8,     o4a);
    st4(aO + (long)n2*64 + q*8 + 4, o4b);
    return;
  }

  // ================= AGG path (blocks 544..1631, backfill) =================
  float* WL = SH;
  int ablk = bid - NGRU;                    // 0..1087
  int tid2 = tid & 255;
  int sub  = tid >> 8;
  int k = tid2 & 15, rl = tid2 >> 4;
  int rbase = ablk*32;
  const int *sI, *nI, *rI; float *sO, *aO; int nb0, uhis;
  if (rbase < NH)          { sI=ahS; nI=ahN; rI=ahR; sO=ws+OFF_SELFH;        aO=ws+OFF_HISLC;       nb0=rbase;        uhis=1; }
  else if (rbase < NH+Bb)  { sI=apS; nI=apN; rI=apR; sO=ws+OFF_SELFPN;       aO=ws+OFF_LCPN;       nb0=rbase-NH;     uhis=0; }
  else                     { sI=anS; nI=anN; rI=anR; sO=ws+OFF_SELFPN+65536; aO=ws+OFF_LCPN+65536; nb0=rbase-NH-Bb;  uhis=0; }
  int n = nb0 + sub*16 + rl;
  int urow = uhis ? (n >> 5) : n;

  for (int i = tid; i < 1024; i += 512){
    st4(&WL[4*i],        ld4(ws + OFF_WCOMB + 4*i));
    st4(&WL[4096 + 4*i], ld4(ws + OFF_WGS   + 4*i));
  }

  const float* es = entity + (long)sI[n]*64;
  long nbI = nI[n*16 + k], rlI = rI[n*16 + k];
  const float* en = entity + nbI*64;

  v2f acc2[32];
  {
    const float* rt = ws + OFF_RELC + rlI*64;
    #pragma unroll
    for (int j4 = 0; j4 < 16; ++j4){
      float4 v = ld4(rt + 4*j4);
      acc2[2*j4]   = (v2f){v.x, v.y};
      acc2[2*j4+1] = (v2f){v.z, v.w};
    }
  }
  __syncthreads();

  // sc = b_gatt + Wg_self@self (lane owns outputs k*4..k*4+3, pk pairs)
  v2f sc2[2];
  {
    float4 bg = ld4(b_gatt + k*4);
    sc2[0] = (v2f){bg.x, bg.y};
    sc2[1] = (v2f){bg.z, bg.w};
  }
  #pragma unroll 2
  for (int j4 = 0; j4 < 16; ++j4){
    float4 s4 = ld4(es + 4*j4);
    float4 w0 = *(const float4*)&WL[4096 + (4*j4+0)*64 + k*4];
    float4 w1 = *(const float4*)&WL[4096 + (4*j4+1)*64 + k*4];
    float4 w2 = *(const float4*)&WL[4096 + (4*j4+2)*64 + k*4];
    float4 w3 = *(const float4*)&WL[4096 + (4*j4+3)*64 + k*4];
    PK4(sc2, w0, s4.x);
    PK4(sc2, w1, s4.y);
    PK4(sc2, w2, s4.z);
    PK4(sc2, w3, s4.w);
  }
  st4(sO + (long)n*64 + k*4, ld4(es + k*4));

  {
    float4 x4 = ld4(en);
    #pragma unroll 2
    for (int j4 = 0; j4 < 16; ++j4){
      float4 xn = ld4(en + 4*((j4+1) & 15));
      v2f xx0; xx0.x = x4.x; xx0.y = x4.x;
      MVJ2(acc2, &WL[(4*j4+0)*64], xx0);
      v2f xx1; xx1.x = x4.y; xx1.y = x4.y;
      MVJ2(acc2, &WL[(4*j4+1)*64], xx1);
      v2f xx2; xx2.x = x4.z; xx2.y = x4.z;
      MVJ2(acc2, &WL[(4*j4+2)*64], xx2);
      v2f xx3; xx3.x = x4.w; xx3.y = x4.w;
      MVJ2(acc2, &WL[(4*j4+3)*64], xx3);
      x4 = xn;
    }
  }

  int gl = (tid & 63) & 48;
  const float* up = ws + OFF_UATT + (long)urow*64;
  float lg = 0.f;
  #pragma unroll
  for (int j4 = 0; j4 < 16; ++j4){
    float4 u4 = ld4(up + 4*j4);
    float s0 = __shfl(sc2[0].x, gl + j4);
    float s1 = __shfl(sc2[0].y, gl + j4);
    float s2 = __shfl(sc2[1].x, gl + j4);
    float s3 = __shfl(sc2[1].y, gl + j4);
    lg += u4.x*tanh_fast(acc2[2*j4].x   + s0);
    lg += u4.y*tanh_fast(acc2[2*j4].y   + s1);
    lg += u4.z*tanh_fast(acc2[2*j4+1].x + s2);
    lg += u4.w*tanh_fast(acc2[2*j4+1].y + s3);
  }
  float mx = lg;
  mx = fmaxf(mx, __shfl_xor(mx, 1)); mx = fmaxf(mx, __shfl_xor(mx, 2));
  mx = fmaxf(mx, __shfl_xor(mx, 4)); mx = fmaxf(mx, __shfl_xor(mx, 8));
  float e = __expf(lg - mx);
  float se = e;
  se += __shfl_xor(se, 1); se += __shfl_xor(se, 2);
  se += __shfl_xor(se, 4); se += __shfl_xor(se, 8);
  float att = __fdividef(e, se);

  __syncthreads();
  for (int i = tid; i < 2048; i += 512)
    st4(&WL[4*i], ld4(ws + OFF_WAGG + 4*i));
  __syncthreads();

  // agg = tanh(W_agg@[self|new_v]+b), lane owns outputs k*4..k*4+3 (pk pairs)
  v2f a2[2];
  {
    float4 ba = ld4(b_agg + k*4);
    a2[0] = (v2f){ba.x, ba.y};
    a2[1] = (v2f){ba.z, ba.w};
  }
  #pragma unroll 2
  for (int j4 = 0; j4 < 16; ++j4){          // self half
    float4 s4 = ld4(es + 4*j4);
    float4 w0 = *(const float4*)&WL[(4*j4+0)*64 + k*4];
    float4 w1 = *(const float4*)&WL[(4*j4+1)*64 + k*4];
    float4 w2 = *(const float4*)&WL[(4*j4+2)*64 + k*4];
    float4 w3 = *(const float4*)&WL[(4*j4+3)*64 + k*4];
    PK4(a2, w0, s4.x);
    PK4(a2, w1, s4.y);
    PK4(a2, w2, s4.z);
    PK4(a2, w3, s4.w);
  }
  #pragma unroll 2
  for (int j4 = 0; j4 < 16; ++j4){          // new_v half via 16-lane butterfly
    float4 x4 = ld4(en + 4*j4);
    float xs[4] = {x4.x, x4.y, x4.z, x4.w};
    #pragma unroll
    for (int jj = 0; jj < 4; ++jj){
      float v = att * xs[jj];
      v += __shfl_xor(v, 1); v += __shfl_xor(v, 2);
      v += __shfl_xor(v, 4); v += __shfl_xor(v, 8);
      float4 wv = *(const float4*)&WL[(64 + 4*j4 + jj)*64 + k*4];
      PK4(a2, wv, v);
    }
  }
  float t0 = tanh_fast(a2[0].x), t1 = tanh_fast(a2[0].y);
  float t2 = tanh_fast(a2[1].x), t3 = tanh_fast(a2[1].y);
  float ss = t0*t0 + t1*t1 + t2*t2 + t3*t3;
  ss += __shfl_xor(ss, 1); ss += __shfl_xor(ss, 2);
  ss += __shfl_xor(ss, 4); ss += __shfl_xor(ss, 8);
  float rn = __fdividef(1.f, fmaxf(sqrtf(ss), 1e-12f));
  float4 o4; o4.x = t0*rn; o4.y = t1*rn; o4.z = t2*rn; o4.w = t3*rn;
  st4(aO + (long)n*64 + k*4, o4);
}

// ---------------- FUSED2: kg + (rsatt⊕umlp) alternating block types (round-9 form) ----------------
__global__ __launch_bounds__(512, 4) void fused2_kernel(
  const int* __restrict__ kh, const int* __restrict__ kr,
  const int* __restrict__ kt, const int* __restrict__ ktn,
  const float* __restrict__ W_iatt, const float* __restrict__ b_iatt,
  const float* __restrict__ b_u,
  const float* __restrict__ entity, const float* __restrict__ relation,
  float* __restrict__ ws, float* __restrict__ out)
{
  __shared__ float WL[4096];                // 16 KB, kg path only
  int tid = threadIdx.x;
  int bid = blockIdx.x;
  int type = bid & 1, rep = bid >> 1;       // 256 reps each

  if (type == 0){
    // ================= KG path (one thread per (r,branch)) =================
    int idx = rep*512 + tid;                // 0..131071
    int br = idx >> 16, r = idx & 65535;
    const int* tailI = br ? ktn : kt;
    for (int i = tid; i < 1024; i += 512)
      st4(&WL[4*i], ld4(ws + OFF_WRE + 4*i));

    long rel = kr[r];
    const float* et = entity + (long)tailI[r]*64;
    v2f acc2[32];
    {
      const float* rt = ws + OFF_RELR + rel*64;
      #pragma unroll
      for (int j4 = 0; j4 < 16; ++j4){
        float4 v = ld4(rt + 4*j4);
        acc2[2*j4]   = (v2f){v.x, v.y};
        acc2[2*j4+1] = (v2f){v.z, v.w};
      }
    }
    __syncthreads();
    {
      float4 x4 = ld4(et);
      #pragma unroll 2
      for (int j4 = 0; j4 < 16; ++j4){
        float4 xn = ld4(et + 4*((j4+1) & 15));
        v2f xx0; xx0.x = x4.x; xx0.y = x4.x;
        MVJ2(acc2, &WL[(4*j4+0)*64], xx0);
        v2f xx1; xx1.x = x4.y; xx1.y = x4.y;
        MVJ2(acc2, &WL[(4*j4+1)*64], xx1);
        v2f xx2; xx2.x = x4.z; xx2.y = x4.z;
        MVJ2(acc2, &WL[(4*j4+2)*64], xx2);
        v2f xx3; xx3.x = x4.w; xx3.y = x4.w;
        MVJ2(acc2, &WL[(4*j4+3)*64], xx3);
        x4 = xn;
      }
    }
    const float* eh = entity + (long)kh[r]*64;
    float s = 0.f;
    #pragma unroll
    for (int j4 = 0; j4 < 16; ++j4){
      float4 h4 = ld4(eh + 4*j4);
      float d0 = h4.x - acc2[2*j4].x,   d1 = h4.y - acc2[2*j4].y;
      float d2 = h4.z - acc2[2*j4+1].x, d3 = h4.w - acc2[2*j4+1].y;
      s += d0*d0 + d1*d1 + d2*d2 + d3*d3;
    }
    ws[OFF_KGS + br*65536 + r] = s;
    return;
  }

  // ================= RSATT+UMLP path (one wave per (b,branch)) =================
  int gw = rep*8 + (tid >> 6), lane = tid & 63;
  int b = gw >> 1, br = gw & 1;
  const float* selfB = ws + OFF_SELFPN + br*65536 + b*64;
  const float* lcB   = ws + OFF_LCPN   + br*65536 + b*64;
  const float* gbB   = ws + OFF_GBPN   + br*65536 + b*64;
  const float* gvec  = ws + OFF_GVEC;
  const float* selfH = ws + OFF_SELFH;
  const float* hisLC = ws + OFF_HISLC;
  const float* hisGB = ws + OFF_HISGB;

  float gd = gvec[lane];
  float ugd = ws[OFF_USERG + b*64 + lane];
  float sv = selfB[lane], lcv = lcB[lane], gbv = gbB[lane];
  float gated = gd*lcv + (1.f - gd)*gbv;
  float part = W_iatt[128+lane]*sv + W_iatt[192+lane]*gated;
  #pragma unroll
  for (int m2 = 1; m2 < 64; m2 <<= 1) part += __shfl_xor(part, m2);
  float itemdot = part + b_iatt[0];

  int m = lane & 31, half = lane >> 5;
  long nrow = (long)(b*32 + m)*64;
  float sh = 0.f;
  if (half == 0){
    for (int j4 = 0; j4 < 16; ++j4){
      float4 h4 = ld4(selfH + nrow + 4*j4);
      float4 w4 = ld4(W_iatt + 4*j4);
      sh += w4.x*h4.x + w4.y*h4.y + w4.z*h4.z + w4.w*h4.w;
    }
  } else {
    for (int j4 = 0; j4 < 16; ++j4){
      float4 l4 = ld4(hisLC + nrow + 4*j4);
      float4 g4 = ld4(hisGB + nrow + 4*j4);
      float4 gg = ld4(gvec + 4*j4);
      float4 w4 = ld4(W_iatt + 64 + 4*j4);
      sh += w4.x*(gg.x*l4.x + (1.f-gg.x)*g4.x);
      sh += w4.y*(gg.y*l4.y + (1.f-gg.y)*g4.y);
      sh += w4.z*(gg.z*l4.z + (1.f-gg.z)*g4.z);
      sh += w4.w*(gg.w*l4.w + (1.f-gg.w)*g4.w);
    }
  }
  sh += __shfl_xor(sh, 32);
  float logit = tanh_fast(sh + itemdot);
  float mxv = logit;
  #pragma unroll
  for (int m2 = 1; m2 < 32; m2 <<= 1) mxv = fmaxf(mxv, __shfl_xor(mxv, m2));
  float e = __expf(logit - mxv);
  float se = e;
  #pragma unroll
  for (int m2 = 1; m2 < 32; m2 <<= 1) se += __shfl_xor(se, m2);
  float att = __fdividef(e, se);

  float u1 = 0.f, u2 = 0.f;
  for (int mm = 0; mm < 32; ++mm){
    float a = __shfl(att, mm);
    long nr = (long)(b*32 + mm)*64;
    float x1 = selfH[nr + lane];
    float x2 = gd*hisLC[nr + lane] + (1.f - gd)*hisGB[nr + lane];
    u1 += a*x1; u2 += a*x2;
  }

  const float* WuT = ws + OFF_WU;
  float acc = b_u[lane];
  for (int j = 0; j < 64; ++j) acc += WuT[j*64 + lane]        * __shfl(ugd, j);
  for (int j = 0; j < 64; ++j) acc += WuT[(64 + j)*64 + lane] * __shfl(u1, j);
  for (int j = 0; j < 64; ++j) acc += WuT[(128 + j)*64 + lane]* __shfl(u2, j);
  float uo = fmaxf(acc, 0.f);
  float ssv = uo*uo;
  #pragma unroll
  for (int m2 = 1; m2 < 64; m2 <<= 1) ssv += __shfl_xor(ssv, m2);
  float rn = __fdividef(1.f, fmaxf(sqrtf(ssv), 1e-12f));
  float nuo = uo*rn;
  float p = ugd*sv + nuo*gated;
  #pragma unroll
  for (int m2 = 1; m2 < 64; m2 <<= 1) p += __shfl_xor(p, m2);
  if (lane == 0) out[br*1024 + b] = p;
}

__global__ void kg_reduce_kernel(float* __restrict__ ws)
{
  int r = blockIdx.x*256 + threadIdx.x;
  float s  = ws[OFF_KGS + r];
  float sn = ws[OFF_KGS + 65536 + r];
  float dif = sn - s;
  float ls = fminf(dif, 0.f) - __logf(1.f + __expf(-fabsf(dif)));
  #pragma unroll
  for (int m2 = 1; m2 < 64; m2 <<= 1) ls += __shfl_xor(ls, m2);
  if ((threadIdx.x & 63) == 0) atomicAdd(ws + OFF_KGSUM, ls);
}

// ---------------- final loss ----------------
__global__ void loss_kernel(const float* __restrict__ ws, float* __restrict__ out)
{
  __shared__ float red[16];
  int t = threadIdx.x;
  float ps = out[t], ns_ = out[1024 + t];
  float dif = ps - ns_;
  float v = fminf(dif, 0.f) - __logf(1.f + __expf(-fabsf(dif)));
  #pragma unroll
  for (int m2 = 1; m2 < 64; m2 <<= 1) v += __shfl_xor(v, m2);
  if ((t & 63) == 0) red[t >> 6] = v;
  __syncthreads();
  if (t == 0){
    float s = 0.f;
    for (int i = 0; i < 16; ++i) s += red[i];
    float rs = -s * (1.f/1024.f);
    float kg = -ws[OFF_KGSUM] * (1.f/65536.f);
    out[2048] = rs + kg;
  }
}

extern "C" void kernel_launch(void* const* d_in, const int* in_sizes, int n_in,
                              void* d_out, int out_size, void* d_ws, size_t ws_size,
                              hipStream_t stream)
{
  const int* user_indices = (const int*)d_in[0];
  const int* ent_his_self = (const int*)d_in[1];
  const int* ent_his_nbr  = (const int*)d_in[2];
  const int* rel_his      = (const int*)d_in[3];
  const int* ent_pos_self = (const int*)d_in[4];
  const int* ent_pos_nbr  = (const int*)d_in[5];
  const int* rel_pos      = (const int*)d_in[6];
  const int* ent_neg_self = (const int*)d_in[7];
  const int* ent_neg_nbr  = (const int*)d_in[8];
  const int* rel_neg      = (const int*)d_in[9];
  const int* gb_his_self  = (const int*)d_in[10];
  const int* gb_his_path  = (const int*)d_in[11];
  const int* gb_pos_self  = (const int*)d_in[12];
  const int* gb_pos_path  = (const int*)d_in[13];
  const int* gb_neg_self  = (const int*)d_in[14];
  const int* gb_neg_path  = (const int*)d_in[15];
  const int* kg_head      = (const int*)d_in[16];
  const int* kg_rel       = (const int*)d_in[17];
  const int* kg_tail      = (const int*)d_in[18];
  const int* kg_tail_neg  = (const int*)d_in[19];
  const float* entity_emb   = (const float*)d_in[20];
  const float* relation_emb = (const float*)d_in[21];
  const float* user_emb     = (const float*)d_in[22];
  const float* gate         = (const float*)d_in[23];
  const float* W_u_mlp      = (const float*)d_in[24];
  const float* b_u_mlp      = (const float*)d_in[25];
  const float* W_re         = (const float*)d_in[26];
  const float* W_agg        = (const float*)d_in[27];
  const float* b_agg        = (const float*)d_in[28];
  const float* W_gatt       = (const float*)d_in[29];
  const float* b_gatt       = (const float*)d_in[30];
  const float* W_iatt       = (const float*)d_in[31];
  const float* b_iatt       = (const float*)d_in[32];
  const float* W_tatt       = (const float*)d_in[33];
  const float* b_tatt       = (const float*)d_in[34];
  const float* W_ih         = (const float*)d_in[35];
  const float* W_hh         = (const float*)d_in[36];
  const float* b_ih         = (const float*)d_in[37];
  const float* b_hh         = (const float*)d_in[38];
  float* ws  = (float*)d_ws;
  float* out = (float*)d_out;

  (void)hipMemsetAsync(ws + OFF_KGSUM, 0, sizeof(float), stream);
  prep1_kernel<<<32, 256, 0, stream>>>(W_tatt, W_gatt, W_re, W_agg, W_u_mlp, W_ih, W_hh, gate, ws);
  prep2_kernel<<<273, 256, 0, stream>>>(relation_emb, user_indices, user_emb, b_tatt, ws);
  // fused gru+agg: gru = blocks 0..543 (critical path, starts first), agg = 544..1631
  fused_kernel<<<NGRU + NAGG, 512, 0, stream>>>(
      gb_his_self, gb_his_path, gb_pos_self, gb_pos_path,
      gb_neg_self, gb_neg_path,
      b_ih, b_hh,
      ws + OFF_WIHP, ws + OFF_WHHP, ws + OFF_WAGP,
      ws + OFF_HISGB, ws + OFF_GBPN,
      ent_his_self, ent_his_nbr, rel_his,
      ent_pos_self, ent_pos_nbr, rel_pos,
      ent_neg_self, ent_neg_nbr, rel_neg,
      b_gatt, b_agg,
      entity_emb, ws);
  // fused kg + rsatt/umlp: 512 blocks, interleave [kg, rs] x 256
  fused2_kernel<<<512, 512, 0, stream>>>(
      kg_head, kg_rel, kg_tail, kg_tail_neg,
      W_iatt, b_iatt, b_u_mlp,
      entity_emb, relation_emb, ws, out);
  kg_reduce_kernel<<<256, 256, 0, stream>>>(ws);
  loss_kernel<<<1, 1024, 0, stream>>>(ws, out);
}

// Round 12
// 594.903 us; speedup vs baseline: 1.0362x; 1.0065x over previous
//
#include <hip/hip_runtime.h>

#define DEV __device__ __forceinline__

#define Dd   64
#define Bb   1024
#define Mm   32
#define Kk   16
#define Ll   8
#define NKGk 65536
#define NH   32768            // B*M
#define ROWS (NH + 2*Bb)      // 34816
#define NGRU (ROWS/64)        // 544 gru blocks
#define NAGG (ROWS/32)        // 1088 agg blocks

typedef float v2f __attribute__((ext_vector_type(2)));

// ---- workspace layout (float offsets) ----
#define OFF_WTATT   0          // 64x64  transposed W_tatt
#define OFF_WGS     4096       // 64x64  transposed W_gatt[:, :64]
#define OFF_WCOMB   8192       // 128x64 transposed (W_gatt[:,64:] @ W_re)
#define OFF_WRE     16384      // 128x64 transposed W_re
#define OFF_WAGG    24576      // 128x64 transposed W_agg
#define OFF_WU      32768      // 192x64 transposed W_u_mlp
#define OFF_GVEC    45056      // 64     sigmoid(gate)
#define OFF_USERG   45120      // 1024x64
#define OFF_UATT    110656     // 1024x64
#define OFF_SELFH   176192     // 32768x64
#define OFF_HISLC   2273344    // 32768x64
#define OFF_HISGB   4370496    // 32768x64
#define OFF_SELFPN  6467648    // 2x1024x64 (pos, then neg)
#define OFF_LCPN    6598720    // 2x1024x64
#define OFF_GBPN    6729792    // 2x1024x64
// KGS lives in the dead ULCPN region (unused since round-8 rsatt+umlp fusion).
#define OFF_KGS     6860864    // 2x65536 kg squared distances -> ends 6992000
#define OFF_KGSUM   7123008    // 1
#define OFF_WIHP    7123072    // 16x8x(4x3x8) = 12288  W_ih packed [jc][w][jj][gate][oi]
#define OFF_WHHP    7135360    // 12288                 W_hh packed
#define OFF_WAGP    7147648    // 32x8x(4x8)   = 8192   W_agg packed [jc][w][jj][oi]
#define OFF_RELC    7155840    // 65x64  (Wcomb_hi @ rel_emb[r])
#define OFF_RELR    7160000    // 65x64  (Wre_hi   @ rel_emb[r])

DEV float4 ld4(const float* p){ return *reinterpret_cast<const float4*>(p); }
DEV void st4(float* p, const float4 v){ *reinterpret_cast<float4*>(p) = v; }

DEV float tanh_fast(float x){
  float cx = fminf(15.f, fmaxf(-15.f, x));
  float e = __expf(2.f*cx);
  return __fdividef(e - 1.f, e + 1.f);
}
DEV float sigmoid_fast(float x){ return __fdividef(1.f, 1.f + __expf(-x)); }

// pk_fma matvec step: acc2[32] v2f pairs
#define MVJ2(ACC2_, WROW_, XX_) { \
  _Pragma("unroll") for (int d4_ = 0; d4_ < 16; ++d4_){ \
    float4 w_ = *(const float4*)((WROW_) + 4*d4_); \
    ACC2_[2*d4_]   += (v2f){w_.x, w_.y}*(XX_); \
    ACC2_[2*d4_+1] += (v2f){w_.z, w_.w}*(XX_); } }

// 4-output pk step: OUT2_[2] v2f accumulators, W4_ float4 of 4 consecutive outputs
#define PK4(OUT2_, W4_, XS_) { \
  v2f xx_; xx_.x = (XS_); xx_.y = (XS_); \
  OUT2_[0] += (v2f){(W4_).x, (W4_).y}*xx_; \
  OUT2_[1] += (v2f){(W4_).z, (W4_).w}*xx_; }

// ---------------- prep1: transposes + packs + gate (32 blocks) ----------------
__global__ void prep1_kernel(const float* __restrict__ W_tatt, const float* __restrict__ W_gatt,
                             const float* __restrict__ W_re, const float* __restrict__ W_agg,
                             const float* __restrict__ W_u, const float* __restrict__ W_ih,
                             const float* __restrict__ W_hh, const float* __restrict__ gate,
                             float* __restrict__ ws)
{
  int g = blockIdx.x*256 + threadIdx.x;     // 0..8191
  for (int i = g; i < 4096; i += 8192){
    int d = i >> 6, j = i & 63;
    ws[OFF_WTATT + j*64 + d] = W_tatt[i];
    ws[OFF_WGS   + j*64 + d] = W_gatt[d*128 + j];
  }
  for (int i = g; i < 8192; i += 8192){
    int j = i >> 6, d = i & 63;
    ws[OFF_WRE  + i] = W_re[d*128 + j];
    ws[OFF_WAGG + i] = W_agg[d*128 + j];
    float s = 0.f;
    for (int dp = 0; dp < 64; ++dp) s += W_gatt[d*128 + 64 + dp] * W_re[dp*128 + j];
    ws[OFF_WCOMB + i] = s;
  }
  for (int i = g; i < 12288; i += 8192){
    int j = i >> 6, d = i & 63;
    ws[OFF_WU + i] = W_u[d*192 + j];
  }
  for (int i = g; i < 12288; i += 8192){
    int jc = i / 768, r1 = i - jc*768;
    int ww = r1 / 96,  r2 = r1 - ww*96;
    int jj = r2 / 24,  r3 = r2 - jj*24;
    int gg = r3 >> 3,  oi = r3 & 7;
    int j = jc*4 + jj, o = gg*64 + ww*8 + oi;
    ws[OFF_WIHP + i] = W_ih[o*64 + j];
    ws[OFF_WHHP + i] = W_hh[o*64 + j];
  }
  for (int i = g; i < 8192; i += 8192){
    int jc = i >> 8, r1 = i & 255;
    int ww = r1 >> 5, r2 = r1 & 31;
    int jj = r2 >> 3, oi = r2 & 7;
    ws[OFF_WAGP + i] = W_agg[(ww*8 + oi)*128 + jc*4 + jj];
  }
  if (g < 64) ws[OFF_GVEC + g] = sigmoid_fast(gate[g]);
}

// ---------------- prep2: rel tables (bid<17) + user gather/u_att (bid>=17) ----------------
__global__ void prep2_kernel(const float* __restrict__ relation,
                             const int* __restrict__ uidx, const float* __restrict__ user_emb,
                             const float* __restrict__ b_tatt, float* __restrict__ ws)
{
  int bid = blockIdx.x;
  if (bid < 17){
    int i = bid*256 + threadIdx.x;          // 4352 >= 4160
    if (i >= 4160) return;
    int r = i >> 6, d = i & 63;
    const float* re = relation + r*64;
    float s1 = 0.f, s2 = 0.f;
    for (int j = 0; j < 64; ++j){
      s1 += ws[OFF_WCOMB + (64+j)*64 + d] * re[j];
      s2 += ws[OFF_WRE   + (64+j)*64 + d] * re[j];
    }
    ws[OFF_RELC + i] = s1;
    ws[OFF_RELR + i] = s2;
    return;
  }
  int gid = (bid - 17)*256 + threadIdx.x;   // 65536 threads
  int b = gid >> 6, lane = gid & 63;
  long ui = uidx[b];
  float ugd = user_emb[ui*64 + lane];
  ws[OFF_USERG + b*64 + lane] = ugd;
  const float* WtT = ws + OFF_WTATT;
  float acc = b_tatt[lane];
  for (int j = 0; j < 64; ++j) acc += WtT[j*64 + lane] * __shfl(ugd, j);
  ws[OFF_UATT + b*64 + lane] = fmaxf(acc, 0.f);
}

// GRU MAC macros (s_load weights via uniform restrict ptr, v_pk_fma pairs)
#define GACC(AR_, AZ_, AN_, WP_, XS_) { \
  v2f xx_; xx_.x = (XS_); xx_.y = (XS_); \
  AR_[0] += (*(const v2f*)((WP_)+ 0))*xx_; AR_[1] += (*(const v2f*)((WP_)+ 2))*xx_; \
  AR_[2] += (*(const v2f*)((WP_)+ 4))*xx_; AR_[3] += (*(const v2f*)((WP_)+ 6))*xx_; \
  AZ_[0] += (*(const v2f*)((WP_)+ 8))*xx_; AZ_[1] += (*(const v2f*)((WP_)+10))*xx_; \
  AZ_[2] += (*(const v2f*)((WP_)+12))*xx_; AZ_[3] += (*(const v2f*)((WP_)+14))*xx_; \
  AN_[0] += (*(const v2f*)((WP_)+16))*xx_; AN_[1] += (*(const v2f*)((WP_)+18))*xx_; \
  AN_[2] += (*(const v2f*)((WP_)+20))*xx_; AN_[3] += (*(const v2f*)((WP_)+22))*xx_; }

#define AGACC(AG_, WP_, XS_) { \
  v2f xx_; xx_.x = (XS_); xx_.y = (XS_); \
  AG_[0] += (*(const v2f*)((WP_)+0))*xx_; AG_[1] += (*(const v2f*)((WP_)+2))*xx_; \
  AG_[2] += (*(const v2f*)((WP_)+4))*xx_; AG_[3] += (*(const v2f*)((WP_)+6))*xx_; }

// ---------------- FUSED gru+agg kernel (round-12: s_setprio on the gru critical path) ----------------
// Round-11 post-mortem: agg pk-ification = exactly 0 (agg fully hidden); fused pinned at
// 412us while total VALU is 199us -> gru's sequential chain loses issue arbitration to
// co-resident agg waves. Classic T5 situation (role-diverse waves on one CU): wrap the
// gru path in s_setprio(1)/(0). gru stalls (s_load, barriers) still yield slots to agg,
// so agg throughput survives in the bubbles. Memory behavior unchanged.
__global__ __launch_bounds__(512, 4) void fused_kernel(
  const int* __restrict__ ghS, const int* __restrict__ ghP,
  const int* __restrict__ gpS, const int* __restrict__ gpP,
  const int* __restrict__ gnS, const int* __restrict__ gnP,
  const float* __restrict__ b_ih, const float* __restrict__ b_hh,
  const float* __restrict__ WIHP, const float* __restrict__ WHHP,
  const float* __restrict__ WAGP,
  float* __restrict__ outHis, float* __restrict__ outPN,
  const int* __restrict__ ahS, const int* __restrict__ ahN, const int* __restrict__ ahR,
  const int* __restrict__ apS, const int* __restrict__ apN, const int* __restrict__ apR,
  const int* __restrict__ anS, const int* __restrict__ anN, const int* __restrict__ anR,
  const float* __restrict__ b_gatt, const float* __restrict__ b_agg,
  const float* __restrict__ entity, float* __restrict__ ws)
{
  __shared__ float SH[8320];                // 33,280 B: gru = hb|xb, agg = WL
  int tid = threadIdx.x;
  int bid = blockIdx.x;

  if (bid < NGRU){
    // ================= GRU path (blocks 0..543, start first, HIGH PRIORITY) =================
    __builtin_amdgcn_s_setprio(1);
    int rep = bid;
    float (*hb)[65] = (float(*)[65])SH;
    float (*xb)[65] = (float(*)[65])(SH + 4160);
    int w = __builtin_amdgcn_readfirstlane(tid >> 6);
    int lane = tid & 63;
    int rbase = rep*64;
    const int *sIv, *pIv; float* aO; int nb0;
    if (rbase < NH)          { sIv=ghS; pIv=ghP; aO=outHis;       nb0=rbase; }
    else if (rbase < NH+Bb)  { sIv=gpS; pIv=gpP; aO=outPN;        nb0=rbase-NH; }
    else                     { sIv=gnS; pIv=gnP; aO=outPN+65536;  nb0=rbase-NH-Bb; }
    int o0 = w*8;
    int nrow = nb0 + lane;

    int pt = pIv[nrow*8];
    int pt_next = pIv[nrow*8 + 1];
    {
      const float* ex = entity + (long)pt*64 + o0;
      float4 xa0 = ld4(ex), xc0 = ld4(ex + 4);
      st4(&xb[lane][o0], xa0);
      st4(&xb[lane][o0+4], xc0);
    }
    __syncthreads();

    #pragma unroll 1
    for (int t = 0; t < 8; ++t){
      float4 xa = {0,0,0,0}, xc = {0,0,0,0};
      if (t < 7){
        const float* ex = entity + (long)pt_next*64 + o0;
        xa = ld4(ex); xc = ld4(ex + 4);
        if (t < 6) pt_next = pIv[nrow*8 + t + 2];
      }
      v2f ar[4], az[4], ah[4];
      #pragma unroll
      for (int p = 0; p < 4; ++p){
        ar[p].x = b_ih[o0+2*p]      + b_hh[o0+2*p];
        ar[p].y = b_ih[o0+2*p+1]    + b_hh[o0+2*p+1];
        az[p].x = b_ih[64+o0+2*p]   + b_hh[64+o0+2*p];
        az[p].y = b_ih[64+o0+2*p+1] + b_hh[64+o0+2*p+1];
        ah[p].x = b_hh[128+o0+2*p];   ah[p].y = b_hh[128+o0+2*p+1];
      }
      if (t){
        #pragma unroll 2
        for (int jc = 0; jc < 16; ++jc){
          const float* wp = WHHP + (jc*8 + w)*96;
          float4 h4 = ld4(&hb[lane][4*jc]);
          GACC(ar, az, ah, wp,      h4.x);
          GACC(ar, az, ah, wp + 24, h4.y);
          GACC(ar, az, ah, wp + 48, h4.z);
          GACC(ar, az, ah, wp + 72, h4.w);
        }
      }
      v2f an[4];
      #pragma unroll
      for (int p = 0; p < 4; ++p){ an[p].x = b_ih[128+o0+2*p]; an[p].y = b_ih[128+o0+2*p+1]; }
      #pragma unroll 2
      for (int jc = 0; jc < 16; ++jc){
        const float* wp = WIHP + (jc*8 + w)*96;
        float4 x4 = ld4(&xb[lane][4*jc]);
        GACC(ar, az, an, wp,      x4.x);
        GACC(ar, az, an, wp + 24, x4.y);
        GACC(ar, az, an, wp + 48, x4.z);
        GACC(ar, az, an, wp + 72, x4.w);
      }
      float hp[8] = {0,0,0,0,0,0,0,0};
      if (t){
        float4 hv0 = ld4(&hb[lane][o0]); float4 hv1 = ld4(&hb[lane][o0+4]);
        hp[0]=hv0.x; hp[1]=hv0.y; hp[2]=hv0.z; hp[3]=hv0.w;
        hp[4]=hv1.x; hp[5]=hv1.y; hp[6]=hv1.z; hp[7]=hv1.w;
      }
      float hn[8];
      #pragma unroll
      for (int p = 0; p < 4; ++p){
        float r0 = sigmoid_fast(ar[p].x), r1 = sigmoid_fast(ar[p].y);
        float z0 = sigmoid_fast(az[p].x), z1 = sigmoid_fast(az[p].y);
        float n0 = tanh_fast(an[p].x + r0*ah[p].x);
        float n1 = tanh_fast(an[p].y + r1*ah[p].y);
        hn[2*p]   = (1.f - z0)*n0 + z0*hp[2*p];
        hn[2*p+1] = (1.f - z1)*n1 + z1*hp[2*p+1];
      }
      __syncthreads();                      // C
      float4 s0 = {hn[0],hn[1],hn[2],hn[3]}, s1 = {hn[4],hn[5],hn[6],hn[7]};
      st4(&hb[lane][o0], s0);
      st4(&hb[lane][o0+4], s1);
      if (t < 7){
        st4(&xb[lane][o0], xa);
        st4(&xb[lane][o0+4], xc);
      }
      __syncthreads();                      // D
    }

    long si = sIv[nrow];
    const float* es = entity + si*64 + o0;
    float4 aa = ld4(es), cc = ld4(es + 4);
    v2f ag[4];
    #pragma unroll
    for (int p = 0; p < 4; ++p){ ag[p].x = b_agg[o0+2*p]; ag[p].y = b_agg[o0+2*p+1]; }
    #pragma unroll 2
    for (int jc = 0; jc < 16; ++jc){
      const float* wp = WAGP + ((16+jc)*8 + w)*32;
      float4 h4 = ld4(&hb[lane][4*jc]);
      AGACC(ag, wp,      h4.x);
      AGACC(ag, wp + 8,  h4.y);
      AGACC(ag, wp + 16, h4.z);
      AGACC(ag, wp + 24, h4.w);
    }
    st4(&xb[lane][o0], aa);
    st4(&xb[lane][o0+4], cc);
    __syncthreads();                        // E
    #pragma unroll 2
    for (int jc = 0; jc < 16; ++jc){
      const float* wp = WAGP + (jc*8 + w)*32;
      float4 x4 = ld4(&xb[lane][4*jc]);
      AGACC(ag, wp,      x4.x);
      AGACC(ag, wp + 8,  x4.y);
      AGACC(ag, wp + 16, x4.z);
      AGACC(ag, wp + 24, x4.w);
    }
    {
      float4 s0 = {tanh_fast(ag[0].x), tanh_fast(ag[0].y), tanh_fast(ag[1].x), tanh_fast(ag[1].y)};
      float4 s1 = {tanh_fast(ag[2].x), tanh_fast(ag[2].y), tanh_fast(ag[3].x), tanh_fast(ag[3].y)};
      st4(&hb[lane][o0], s0);
      st4(&hb[lane][o0+4], s1);
    }
    __syncthreads();                        // F
    int q = tid & 7, r = tid >> 3;
    float4 v0 = ld4(&hb[r][q*8]);
    float4 v1 = ld4(&hb[r][q*8+4]);
    float ss = v0.x*v0.x + v0.y*v0.y + v0.z*v0.z + v0.w*v0.w
             + v1.x*v1.x + v1.y*v1.y + v1.z*v1.z + v1.w*v1.w;
    ss += __shfl_xor(ss, 1); ss += __shfl_xor(ss, 2); ss += __shfl_xor(ss, 4);
    float rn = __fdividef(1.f, fmaxf(sqrtf(ss), 1e-12f));
    int n2 = nb0 + r;
    float4 o4a = {v0.x*rn, v0.y*rn, v0.z*rn, v0.w*rn};
    float4 o4b = {v1.x*rn, v1.y*rn, v1.z*rn, v1.w*rn};
    st4(aO + (long)n2*64 + q*8,     o4a);
    st4(aO + (long)n2*64 + q*8 + 4, o4b);
    __builtin_amdgcn_s_setprio(0);
    return;
  }

  // ================= AGG path (blocks 544..1631, backfill, prio 0) =================
  float* WL = SH;
  int ablk = bid - NGRU;                    // 0..1087
  int tid2 = tid & 255;
  int sub  = tid >> 8;
  int k = tid2 & 15, rl = tid2 >> 4;
  int rbase = ablk*32;
  const int *sI, *nI, *rI; float *sO, *aO; int nb0, uhis;
  if (rbase < NH)          { sI=ahS; nI=ahN; rI=ahR; sO=ws+OFF_SELFH;        aO=ws+OFF_HISLC;       nb0=rbase;        uhis=1; }
  else if (rbase < NH+Bb)  { sI=apS; nI=apN; rI=apR; sO=ws+OFF_SELFPN;       aO=ws+OFF_LCPN;       nb0=rbase-NH;     uhis=0; }
  else                     { sI=anS; nI=anN; rI=anR; sO=ws+OFF_SELFPN+65536; aO=ws+OFF_LCPN+65536; nb0=rbase-NH-Bb;  uhis=0; }
  int n = nb0 + sub*16 + rl;
  int urow = uhis ? (n >> 5) : n;

  for (int i = tid; i < 1024; i += 512){
    st4(&WL[4*i],        ld4(ws + OFF_WCOMB + 4*i));
    st4(&WL[4096 + 4*i], ld4(ws + OFF_WGS   + 4*i));
  }

  const float* es = entity + (long)sI[n]*64;
  long nbI = nI[n*16 + k], rlI = rI[n*16 + k];
  const float* en = entity + nbI*64;

  v2f acc2[32];
  {
    const float* rt = ws + OFF_RELC + rlI*64;
    #pragma unroll
    for (int j4 = 0; j4 < 16; ++j4){
      float4 v = ld4(rt + 4*j4);
      acc2[2*j4]   = (v2f){v.x, v.y};
      acc2[2*j4+1] = (v2f){v.z, v.w};
    }
  }
  __syncthreads();

  // sc = b_gatt + Wg_self@self (lane owns outputs k*4..k*4+3, pk pairs)
  v2f sc2[2];
  {
    float4 bg = ld4(b_gatt + k*4);
    sc2[0] = (v2f){bg.x, bg.y};
    sc2[1] = (v2f){bg.z, bg.w};
  }
  #pragma unroll 2
  for (int j4 = 0; j4 < 16; ++j4){
    float4 s4 = ld4(es + 4*j4);
    float4 w0 = *(const float4*)&WL[4096 + (4*j4+0)*64 + k*4];
    float4 w1 = *(const float4*)&WL[4096 + (4*j4+1)*64 + k*4];
    float4 w2 = *(const float4*)&WL[4096 + (4*j4+2)*64 + k*4];
    float4 w3 = *(const float4*)&WL[4096 + (4*j4+3)*64 + k*4];
    PK4(sc2, w0, s4.x);
    PK4(sc2, w1, s4.y);
    PK4(sc2, w2, s4.z);
    PK4(sc2, w3, s4.w);
  }
  st4(sO + (long)n*64 + k*4, ld4(es + k*4));

  {
    float4 x4 = ld4(en);
    #pragma unroll 2
    for (int j4 = 0; j4 < 16; ++j4){
      float4 xn = ld4(en + 4*((j4+1) & 15));
      v2f xx0; xx0.x = x4.x; xx0.y = x4.x;
      MVJ2(acc2, &WL[(4*j4+0)*64], xx0);
      v2f xx1; xx1.x = x4.y; xx1.y = x4.y;
      MVJ2(acc2, &WL[(4*j4+1)*64], xx1);
      v2f xx2; xx2.x = x4.z; xx2.y = x4.z;
      MVJ2(acc2, &WL[(4*j4+2)*64], xx2);
      v2f xx3; xx3.x = x4.w; xx3.y = x4.w;
      MVJ2(acc2, &WL[(4*j4+3)*64], xx3);
      x4 = xn;
    }
  }

  int gl = (tid & 63) & 48;
  const float* up = ws + OFF_UATT + (long)urow*64;
  float lg = 0.f;
  #pragma unroll
  for (int j4 = 0; j4 < 16; ++j4){
    float4 u4 = ld4(up + 4*j4);
    float s0 = __shfl(sc2[0].x, gl + j4);
    float s1 = __shfl(sc2[0].y, gl + j4);
    float s2 = __shfl(sc2[1].x, gl + j4);
    float s3 = __shfl(sc2[1].y, gl + j4);
    lg += u4.x*tanh_fast(acc2[2*j4].x   + s0);
    lg += u4.y*tanh_fast(acc2[2*j4].y   + s1);
    lg += u4.z*tanh_fast(acc2[2*j4+1].x + s2);
    lg += u4.w*tanh_fast(acc2[2*j4+1].y + s3);
  }
  float mx = lg;
  mx = fmaxf(mx, __shfl_xor(mx, 1)); mx = fmaxf(mx, __shfl_xor(mx, 2));
  mx = fmaxf(mx, __shfl_xor(mx, 4)); mx = fmaxf(mx, __shfl_xor(mx, 8));
  float e = __expf(lg - mx);
  float se = e;
  se += __shfl_xor(se, 1); se += __shfl_xor(se, 2);
  se += __shfl_xor(se, 4); se += __shfl_xor(se, 8);
  float att = __fdividef(e, se);

  __syncthreads();
  for (int i = tid; i < 2048; i += 512)
    st4(&WL[4*i], ld4(ws + OFF_WAGG + 4*i));
  __syncthreads();

  // agg = tanh(W_agg@[self|new_v]+b), lane owns outputs k*4..k*4+3 (pk pairs)
  v2f a2[2];
  {
    float4 ba = ld4(b_agg + k*4);
    a2[0] = (v2f){ba.x, ba.y};
    a2[1] = (v2f){ba.z, ba.w};
  }
  #pragma unroll 2
  for (int j4 = 0; j4 < 16; ++j4){          // self half
    float4 s4 = ld4(es + 4*j4);
    float4 w0 = *(const float4*)&WL[(4*j4+0)*64 + k*4];
    float4 w1 = *(const float4*)&WL[(4*j4+1)*64 + k*4];
    float4 w2 = *(const float4*)&WL[(4*j4+2)*64 + k*4];
    float4 w3 = *(const float4*)&WL[(4*j4+3)*64 + k*4];
    PK4(a2, w0, s4.x);
    PK4(a2, w1, s4.y);
    PK4(a2, w2, s4.z);
    PK4(a2, w3, s4.w);
  }
  #pragma unroll 2
  for (int j4 = 0; j4 < 16; ++j4){          // new_v half via 16-lane butterfly
    float4 x4 = ld4(en + 4*j4);
    float xs[4] = {x4.x, x4.y, x4.z, x4.w};
    #pragma unroll
    for (int jj = 0; jj < 4; ++jj){
      float v = att * xs[jj];
      v += __shfl_xor(v, 1); v += __shfl_xor(v, 2);
      v += __shfl_xor(v, 4); v += __shfl_xor(v, 8);
      float4 wv = *(const float4*)&WL[(64 + 4*j4 + jj)*64 + k*4];
      PK4(a2, wv, v);
    }
  }
  float t0 = tanh_fast(a2[0].x), t1 = tanh_fast(a2[0].y);
  float t2 = tanh_fast(a2[1].x), t3 = tanh_fast(a2[1].y);
  float ss = t0*t0 + t1*t1 + t2*t2 + t3*t3;
  ss += __shfl_xor(ss, 1); ss += __shfl_xor(ss, 2);
  ss += __shfl_xor(ss, 4); ss += __shfl_xor(ss, 8);
  float rn = __fdividef(1.f, fmaxf(sqrtf(ss), 1e-12f));
  float4 o4; o4.x = t0*rn; o4.y = t1*rn; o4.z = t2*rn; o4.w = t3*rn;
  st4(aO + (long)n*64 + k*4, o4);
}

// ---------------- FUSED2: kg + (rsatt⊕umlp) alternating block types ----------------
__global__ __launch_bounds__(512, 4) void fused2_kernel(
  const int* __restrict__ kh, const int* __restrict__ kr,
  const int* __restrict__ kt, const int* __restrict__ ktn,
  const float* __restrict__ W_iatt, const float* __restrict__ b_iatt,
  const float* __restrict__ b_u,
  const float* __restrict__ entity, const float* __restrict__ relation,
  float* __restrict__ ws, float* __restrict__ out)
{
  __shared__ float WL[4096];                // 16 KB, kg path only
  int tid = threadIdx.x;
  int bid = blockIdx.x;
  int type = bid & 1, rep = bid >> 1;       // 256 reps each

  if (type == 0){
    // ================= KG path (one thread per (r,branch)) =================
    int idx = rep*512 + tid;                // 0..131071
    int br = idx >> 16, r = idx & 65535;
    const int* tailI = br ? ktn : kt;
    for (int i = tid; i < 1024; i += 512)
      st4(&WL[4*i], ld4(ws + OFF_WRE + 4*i));

    long rel = kr[r];
    const float* et = entity + (long)tailI[r]*64;
    v2f acc2[32];
    {
      const float* rt = ws + OFF_RELR + rel*64;
      #pragma unroll
      for (int j4 = 0; j4 < 16; ++j4){
        float4 v = ld4(rt + 4*j4);
        acc2[2*j4]   = (v2f){v.x, v.y};
        acc2[2*j4+1] = (v2f){v.z, v.w};
      }
    }
    __syncthreads();
    {
      float4 x4 = ld4(et);
      #pragma unroll 2
      for (int j4 = 0; j4 < 16; ++j4){
        float4 xn = ld4(et + 4*((j4+1) & 15));
        v2f xx0; xx0.x = x4.x; xx0.y = x4.x;
        MVJ2(acc2, &WL[(4*j4+0)*64], xx0);
        v2f xx1; xx1.x = x4.y; xx1.y = x4.y;
        MVJ2(acc2, &WL[(4*j4+1)*64], xx1);
        v2f xx2; xx2.x = x4.z; xx2.y = x4.z;
        MVJ2(acc2, &WL[(4*j4+2)*64], xx2);
        v2f xx3; xx3.x = x4.w; xx3.y = x4.w;
        MVJ2(acc2, &WL[(4*j4+3)*64], xx3);
        x4 = xn;
      }
    }
    const float* eh = entity + (long)kh[r]*64;
    float s = 0.f;
    #pragma unroll
    for (int j4 = 0; j4 < 16; ++j4){
      float4 h4 = ld4(eh + 4*j4);
      float d0 = h4.x - acc2[2*j4].x,   d1 = h4.y - acc2[2*j4].y;
      float d2 = h4.z - acc2[2*j4+1].x, d3 = h4.w - acc2[2*j4+1].y;
      s += d0*d0 + d1*d1 + d2*d2 + d3*d3;
    }
    ws[OFF_KGS + br*65536 + r] = s;
    return;
  }

  // ================= RSATT+UMLP path (one wave per (b,branch)) =================
  int gw = rep*8 + (tid >> 6), lane = tid & 63;
  int b = gw >> 1, br = gw & 1;
  const float* selfB = ws + OFF_SELFPN + br*65536 + b*64;
  const float* lcB   = ws + OFF_LCPN   + br*65536 + b*64;
  const float* gbB   = ws + OFF_GBPN   + br*65536 + b*64;
  const float* gvec  = ws + OFF_GVEC;
  const float* selfH = ws + OFF_SELFH;
  const float* hisLC = ws + OFF_HISLC;
  const float* hisGB = ws + OFF_HISGB;

  float gd = gvec[lane];
  float ugd = ws[OFF_USERG + b*64 + lane];
  float sv = selfB[lane], lcv = lcB[lane], gbv = gbB[lane];
  float gated = gd*lcv + (1.f - gd)*gbv;
  float part = W_iatt[128+lane]*sv + W_iatt[192+lane]*gated;
  #pragma unroll
  for (int m2 = 1; m2 < 64; m2 <<= 1) part += __shfl_xor(part, m2);
  float itemdot = part + b_iatt[0];

  int m = lane & 31, half = lane >> 5;
  long nrow = (long)(b*32 + m)*64;
  float sh = 0.f;
  if (half == 0){
    for (int j4 = 0; j4 < 16; ++j4){
      float4 h4 = ld4(selfH + nrow + 4*j4);
      float4 w4 = ld4(W_iatt + 4*j4);
      sh += w4.x*h4.x + w4.y*h4.y + w4.z*h4.z + w4.w*h4.w;
    }
  } else {
    for (int j4 = 0; j4 < 16; ++j4){
      float4 l4 = ld4(hisLC + nrow + 4*j4);
      float4 g4 = ld4(hisGB + nrow + 4*j4);
      float4 gg = ld4(gvec + 4*j4);
      float4 w4 = ld4(W_iatt + 64 + 4*j4);
      sh += w4.x*(gg.x*l4.x + (1.f-gg.x)*g4.x);
      sh += w4.y*(gg.y*l4.y + (1.f-gg.y)*g4.y);
      sh += w4.z*(gg.z*l4.z + (1.f-gg.z)*g4.z);
      sh += w4.w*(gg.w*l4.w + (1.f-gg.w)*g4.w);
    }
  }
  sh += __shfl_xor(sh, 32);
  float logit = tanh_fast(sh + itemdot);
  float mxv = logit;
  #pragma unroll
  for (int m2 = 1; m2 < 32; m2 <<= 1) mxv = fmaxf(mxv, __shfl_xor(mxv, m2));
  float e = __expf(logit - mxv);
  float se = e;
  #pragma unroll
  for (int m2 = 1; m2 < 32; m2 <<= 1) se += __shfl_xor(se, m2);
  float att = __fdividef(e, se);

  float u1 = 0.f, u2 = 0.f;
  for (int mm = 0; mm < 32; ++mm){
    float a = __shfl(att, mm);
    long nr = (long)(b*32 + mm)*64;
    float x1 = selfH[nr + lane];
    float x2 = gd*hisLC[nr + lane] + (1.f - gd)*hisGB[nr + lane];
    u1 += a*x1; u2 += a*x2;
  }

  const float* WuT = ws + OFF_WU;
  float acc = b_u[lane];
  for (int j = 0; j < 64; ++j) acc += WuT[j*64 + lane]        * __shfl(ugd, j);
  for (int j = 0; j < 64; ++j) acc += WuT[(64 + j)*64 + lane] * __shfl(u1, j);
  for (int j = 0; j < 64; ++j) acc += WuT[(128 + j)*64 + lane]* __shfl(u2, j);
  float uo = fmaxf(acc, 0.f);
  float ssv = uo*uo;
  #pragma unroll
  for (int m2 = 1; m2 < 64; m2 <<= 1) ssv += __shfl_xor(ssv, m2);
  float rn = __fdividef(1.f, fmaxf(sqrtf(ssv), 1e-12f));
  float nuo = uo*rn;
  float p = ugd*sv + nuo*gated;
  #pragma unroll
  for (int m2 = 1; m2 < 64; m2 <<= 1) p += __shfl_xor(p, m2);
  if (lane == 0) out[br*1024 + b] = p;
}

__global__ void kg_reduce_kernel(float* __restrict__ ws)
{
  int r = blockIdx.x*256 + threadIdx.x;
  float s  = ws[OFF_KGS + r];
  float sn = ws[OFF_KGS + 65536 + r];
  float dif = sn - s;
  float ls = fminf(dif, 0.f) - __logf(1.f + __expf(-fabsf(dif)));
  #pragma unroll
  for (int m2 = 1; m2 < 64; m2 <<= 1) ls += __shfl_xor(ls, m2);
  if ((threadIdx.x & 63) == 0) atomicAdd(ws + OFF_KGSUM, ls);
}

// ---------------- final loss ----------------
__global__ void loss_kernel(const float* __restrict__ ws, float* __restrict__ out)
{
  __shared__ float red[16];
  int t = threadIdx.x;
  float ps = out[t], ns_ = out[1024 + t];
  float dif = ps - ns_;
  float v = fminf(dif, 0.f) - __logf(1.f + __expf(-fabsf(dif)));
  #pragma unroll
  for (int m2 = 1; m2 < 64; m2 <<= 1) v += __shfl_xor(v, m2);
  if ((t & 63) == 0) red[t >> 6] = v;
  __syncthreads();
  if (t == 0){
    float s = 0.f;
    for (int i = 0; i < 16; ++i) s += red[i];
    float rs = -s * (1.f/1024.f);
    float kg = -ws[OFF_KGSUM] * (1.f/65536.f);
    out[2048] = rs + kg;
  }
}

extern "C" void kernel_launch(void* const* d_in, const int* in_sizes, int n_in,
                              void* d_out, int out_size, void* d_ws, size_t ws_size,
                              hipStream_t stream)
{
  const int* user_indices = (const int*)d_in[0];
  const int* ent_his_self = (const int*)d_in[1];
  const int* ent_his_nbr  = (const int*)d_in[2];
  const int* rel_his      = (const int*)d_in[3];
  const int* ent_pos_self = (const int*)d_in[4];
  const int* ent_pos_nbr  = (const int*)d_in[5];
  const int* rel_pos      = (const int*)d_in[6];
  const int* ent_neg_self = (const int*)d_in[7];
  const int* ent_neg_nbr  = (const int*)d_in[8];
  const int* rel_neg      = (const int*)d_in[9];
  const int* gb_his_self  = (const int*)d_in[10];
  const int* gb_his_path  = (const int*)d_in[11];
  const int* gb_pos_self  = (const int*)d_in[12];
  const int* gb_pos_path  = (const int*)d_in[13];
  const int* gb_neg_self  = (const int*)d_in[14];
  const int* gb_neg_path  = (const int*)d_in[15];
  const int* kg_head      = (const int*)d_in[16];
  const int* kg_rel       = (const int*)d_in[17];
  const int* kg_tail      = (const int*)d_in[18];
  const int* kg_tail_neg  = (const int*)d_in[19];
  const float* entity_emb   = (const float*)d_in[20];
  const float* relation_emb = (const float*)d_in[21];
  const float* user_emb     = (const float*)d_in[22];
  const float* gate         = (const float*)d_in[23];
  const float* W_u_mlp      = (const float*)d_in[24];
  const float* b_u_mlp      = (const float*)d_in[25];
  const float* W_re         = (const float*)d_in[26];
  const float* W_agg        = (const float*)d_in[27];
  const float* b_agg        = (const float*)d_in[28];
  const float* W_gatt       = (const float*)d_in[29];
  const float* b_gatt       = (const float*)d_in[30];
  const float* W_iatt       = (const float*)d_in[31];
  const float* b_iatt       = (const float*)d_in[32];
  const float* W_tatt       = (const float*)d_in[33];
  const float* b_tatt       = (const float*)d_in[34];
  const float* W_ih         = (const float*)d_in[35];
  const float* W_hh         = (const float*)d_in[36];
  const float* b_ih         = (const float*)d_in[37];
  const float* b_hh         = (const float*)d_in[38];
  float* ws  = (float*)d_ws;
  float* out = (float*)d_out;

  (void)hipMemsetAsync(ws + OFF_KGSUM, 0, sizeof(float), stream);
  prep1_kernel<<<32, 256, 0, stream>>>(W_tatt, W_gatt, W_re, W_agg, W_u_mlp, W_ih, W_hh, gate, ws);
  prep2_kernel<<<273, 256, 0, stream>>>(relation_emb, user_indices, user_emb, b_tatt, ws);
  // fused gru+agg: gru = blocks 0..543 (critical path, prio 1), agg = 544..1631 (prio 0)
  fused_kernel<<<NGRU + NAGG, 512, 0, stream>>>(
      gb_his_self, gb_his_path, gb_pos_self, gb_pos_path,
      gb_neg_self, gb_neg_path,
      b_ih, b_hh,
      ws + OFF_WIHP, ws + OFF_WHHP, ws + OFF_WAGP,
      ws + OFF_HISGB, ws + OFF_GBPN,
      ent_his_self, ent_his_nbr, rel_his,
      ent_pos_self, ent_pos_nbr, rel_pos,
      ent_neg_self, ent_neg_nbr, rel_neg,
      b_gatt, b_agg,
      entity_emb, ws);
  // fused kg + rsatt/umlp: 512 blocks, interleave [kg, rs] x 256
  fused2_kernel<<<512, 512, 0, stream>>>(
      kg_head, kg_rel, kg_tail, kg_tail_neg,
      W_iatt, b_iatt, b_u_mlp,
      entity_emb, relation_emb, ws, out);
  kg_reduce_kernel<<<256, 256, 0, stream>>>(ws);
  loss_kernel<<<1, 1024, 0, stream>>>(ws, out);
}